// Round 15
// baseline (533.875 us; speedup 1.0000x reference)
//
#include <hip/hip_runtime.h>
#include <hip/hip_bf16.h>
#include <hip/hip_fp8.h>

#define N_NODES 100000
#define N_EDGES 3200000
#define IN_DIM  128
#define HID     32
#define NCLUS   30
#define EDGE_BLOCKS 12500 // ceil(3200000/256)
#define GRP_BLOCKS  12500 // 12500*8 = 100000 nodes EXACT (no tail block)

// ---- counting-sort geometry ----
#define BUCK_SHIFT 7
#define BUCK_W     128
#define NBUCK      782
#define PB         128                 // pass-1 blocks (128B per (block,bucket) run)
#define EPB        25000               // 128*25000 = 3.2M exact
#define SEG_CAP    8192
#define FTPB       512                 // threads per fused block

// ---- gemm1 row-per-lane geometry: 512 rows/block (lane owns a row; W1 in LDS) ----
#define G1A_BLK    98                  // 98*512 = 50176 rows in k_f1
#define G1A_ROWS   50176
#define G1B_BLK    98                  // rows [50176,100000) guarded, in k_f2

// ---- mse geometry: 3125*256*4 = 3.2M EXACT (no guards, standalone) ----
#define MSE_BLOCKS 3125
#define MSE_S      (MSE_BLOCKS * 256)  // 800000

__device__ __forceinline__ float bf2f(__hip_bfloat16 v) { return __bfloat162float(v); }

// fp8 e4m3 (OCP) encode/decode via HW cvt
__device__ __forceinline__ unsigned char enc8(float v) {
  __hip_fp8_e4m3 t(v); return (unsigned char)t.__x;
}
__device__ __forceinline__ float dec8(unsigned b) {
  __hip_fp8_e4m3 t; t.__x = (__hip_fp8_storage_t)b; return (float)t;
}
__device__ __forceinline__ float dot4_fp8(unsigned a, unsigned b) {
  float r = 0.0f;
  #pragma unroll
  for (int k = 0; k < 4; k++)
    r += dec8((a >> (8 * k)) & 0xffu) * dec8((b >> (8 * k)) & 0xffu);
  return r;
}

// packed dot of 4 fp8 pairs: HW packed cvt (2 floats/instr, OCP e4m3 on gfx950)
typedef float floatx2 __attribute__((ext_vector_type(2)));
__device__ __forceinline__ float dot4p(unsigned a, unsigned b) {
#if __has_builtin(__builtin_amdgcn_cvt_pk_f32_fp8)
  floatx2 al = __builtin_amdgcn_cvt_pk_f32_fp8((int)a, false);
  floatx2 ah = __builtin_amdgcn_cvt_pk_f32_fp8((int)a, true);
  floatx2 bl = __builtin_amdgcn_cvt_pk_f32_fp8((int)b, false);
  floatx2 bh = __builtin_amdgcn_cvt_pk_f32_fp8((int)b, true);
  return al[0]*bl[0] + al[1]*bl[1] + ah[0]*bh[0] + ah[1]*bh[1];
#else
  return dot4_fp8(a, b);
#endif
}
__device__ __forceinline__ float rowdot(const uint4& a0, const uint4& a1,
                                        const uint4& b0, const uint4& b1) {
  return dot4p(a0.x, b0.x) + dot4p(a0.y, b0.y) + dot4p(a0.z, b0.z) + dot4p(a0.w, b0.w)
       + dot4p(a1.x, b1.x) + dot4p(a1.y, b1.y) + dot4p(a1.z, b1.z) + dot4p(a1.w, b1.w);
}

// scale a packed pair of bf16 by sc (RNE via __float2bfloat16)
__device__ __forceinline__ unsigned sc2(unsigned u, float sc) {
  __hip_bfloat16 h0 = *reinterpret_cast<__hip_bfloat16*>(&u);
  unsigned uh = u >> 16;
  __hip_bfloat16 h1 = *reinterpret_cast<__hip_bfloat16*>(&uh);
  __hip_bfloat16 r0 = __float2bfloat16(__bfloat162float(h0) * sc);
  __hip_bfloat16 r1 = __float2bfloat16(__bfloat162float(h1) * sc);
  unsigned a = *reinterpret_cast<unsigned short*>(&r0);
  unsigned b = *reinterpret_cast<unsigned short*>(&r1);
  return a | (b << 16);
}

// edge_index accessor: f=0 -> int32 layout, f=1 -> int64 layout (read low word)
__device__ __forceinline__ int edge_at(const int* ei, int row, int e, int f) {
  int v = ei[(row * N_EDGES + e) << f];
  return min(max(v, 0), N_NODES - 1);
}

// ---- detect int32 vs int64 edge_index + zero loss scalars ----
__global__ void k_detect(const unsigned int* ei, int* flag, float* colsum, double* msed) {
  int t = threadIdx.x;
  if (t < 32) colsum[t] = 0.0f;
  if (t == 32) *msed = 0.0;
  if (t == 0) {
    int zeros = 0;
    for (int i = 1; i < 128; i += 2) zeros += (ei[i] == 0u) ? 1 : 0;
    *flag = (zeros >= 48) ? 1 : 0;
  }
}

// ---- zero cnt + loss scalars (fallback path) ----
__global__ void k_zeroall(int* cnt, float* colsum, double* msed) {
  int t = blockIdx.x * blockDim.x + threadIdx.x;
  if (t < N_NODES) cnt[t] = 0;
  if (t < 32) colsum[t] = 0.0f;
  if (t == 32) *msed = 0.0;
}

// ---- GEMM1 row-per-lane body: lane owns row n; x per-lane float4 (distinct lines),
//      W1 broadcast from LDS. UNSCALED bf16 out (dinv applied in k_pass2 rescale). ----
__device__ __forceinline__ void gemm1_rpl(int gb, int row_off, const float* x,
                                          const float* Wl, __hip_bfloat16* G1) {
  int n = row_off + gb * FTPB + threadIdx.x;
  if (n >= N_NODES) return;
  float acc[32];
  #pragma unroll
  for (int j = 0; j < 32; j++) acc[j] = 0.0f;
  const float4* xp = (const float4*)(x + (size_t)n * IN_DIM);
  #pragma unroll
  for (int kc = 0; kc < 4; kc++) {          // 4 chunks of 32 k
    float4 xv[8];
    #pragma unroll
    for (int q = 0; q < 8; q++) xv[q] = xp[kc * 8 + q];
    #pragma unroll
    for (int q = 0; q < 8; q++) {
      #pragma unroll
      for (int e = 0; e < 4; e++) {
        float xk = (e == 0) ? xv[q].x : (e == 1) ? xv[q].y : (e == 2) ? xv[q].z : xv[q].w;
        const float4* wr = (const float4*)(Wl + (kc * 32 + q * 4 + e) * HID);
        #pragma unroll
        for (int jv = 0; jv < 8; jv++) {    // 8 x float4 = 32 cols
          float4 w4 = wr[jv];               // uniform addr -> LDS broadcast
          acc[4*jv+0] += xk * w4.x;
          acc[4*jv+1] += xk * w4.y;
          acc[4*jv+2] += xk * w4.z;
          acc[4*jv+3] += xk * w4.w;
        }
      }
    }
  }
  unsigned pk[16];
  #pragma unroll
  for (int jp = 0; jp < 16; jp++) {
    __hip_bfloat16 l0 = __float2bfloat16(acc[2*jp]);
    __hip_bfloat16 l1 = __float2bfloat16(acc[2*jp+1]);
    unsigned a = *reinterpret_cast<unsigned short*>(&l0);
    unsigned b = *reinterpret_cast<unsigned short*>(&l1);
    pk[jp] = a | (b << 16);
  }
  uint4* dst = (uint4*)(G1 + (size_t)n * 32);   // 64B = lane-owned line
  dst[0] = make_uint4(pk[0], pk[1], pk[2], pk[3]);
  dst[1] = make_uint4(pk[4], pk[5], pk[6], pk[7]);
  dst[2] = make_uint4(pk[8], pk[9], pk[10], pk[11]);
  dst[3] = make_uint4(pk[12], pk[13], pk[14], pk[15]);
}

// ---- FUSED 1: blocks [0,PB) = LDS bucket histogram (4-deep prefetch); rest = gemmA ----
__global__ void __launch_bounds__(FTPB) k_f1(const int* ei, const int* flag, int* H,
                                             const float* x, const float* W1, __hip_bfloat16* G1) {
  __shared__ float smem[IN_DIM * HID];           // 16KB: Wl for gemm / h[] for hist
  int t = threadIdx.x;
  if (blockIdx.x >= PB) {
    for (int i = t; i < IN_DIM * HID; i += FTPB) smem[i] = W1[i];
    __syncthreads();
    gemm1_rpl(blockIdx.x - PB, 0, x, smem, G1);
    return;
  }
  int* h = (int*)smem;
  int p = blockIdx.x;
  for (int i = t; i < NBUCK; i += FTPB) h[i] = 0;
  __syncthreads();
  int f = *flag;
  int base = p * EPB;
  int i = t;
  for (; i + 3 * FTPB < EPB; i += 4 * FTPB) {
    int d0 = edge_at(ei, 1, base + i,            f);
    int d1 = edge_at(ei, 1, base + i + FTPB,     f);
    int d2 = edge_at(ei, 1, base + i + 2 * FTPB, f);
    int d3 = edge_at(ei, 1, base + i + 3 * FTPB, f);
    atomicAdd(&h[d0 >> BUCK_SHIFT], 1);
    atomicAdd(&h[d1 >> BUCK_SHIFT], 1);
    atomicAdd(&h[d2 >> BUCK_SHIFT], 1);
    atomicAdd(&h[d3 >> BUCK_SHIFT], 1);
  }
  for (; i < EPB; i += FTPB) {
    int d = edge_at(ei, 1, base + i, f);
    atomicAdd(&h[d >> BUCK_SHIFT], 1);
  }
  __syncthreads();
  for (int q = t; q < NBUCK; q += FTPB) H[p * NBUCK + q] = h[q];
}

// ---- sort scan A: column-scan of H over PB blocks -> exclusive in place + bucket totals ----
__global__ void __launch_bounds__(PB) k_hscan(int* H, int* tot) {
  __shared__ int s[PB];
  int b = blockIdx.x, t = threadIdx.x;
  int v = H[t * NBUCK + b];
  s[t] = v; __syncthreads();
  for (int off = 1; off < PB; off <<= 1) {
    int u = (t >= off) ? s[t - off] : 0;
    __syncthreads();
    s[t] += u;
    __syncthreads();
  }
  H[t * NBUCK + b] = s[t] - v;               // exclusive prefix within bucket column
  if (t == PB - 1) tot[b] = s[t];
}

// ---- sort scan B: exclusive scan of bucket totals -> bstart[0..NBUCK] ----
__global__ void __launch_bounds__(1024) k_bscan(const int* tot, int* bstart) {
  __shared__ int s[1024];
  int t = threadIdx.x;
  int v = (t < NBUCK) ? tot[t] : 0;
  s[t] = v; __syncthreads();
  for (int off = 1; off < 1024; off <<= 1) {
    int u = (t >= off) ? s[t - off] : 0;
    __syncthreads();
    s[t] += u;
    __syncthreads();
  }
  if (t < NBUCK) bstart[t] = s[t] - v;
  if (t == NBUCK - 1) bstart[NBUCK] = s[t];  // = N_EDGES
}

// ---- FUSED 2: blocks [0,PB) = scatter (4-deep prefetch); rest = gemmB ----
__global__ void __launch_bounds__(FTPB) k_f2(const int* ei, const int* flag, const int* H,
                                             const int* bstart, unsigned* sorted,
                                             const float* x, const float* W1, __hip_bfloat16* G1) {
  __shared__ float smem[IN_DIM * HID];           // 16KB: Wl for gemm / cur[] for scatter
  int t = threadIdx.x;
  if (blockIdx.x >= PB) {
    for (int i = t; i < IN_DIM * HID; i += FTPB) smem[i] = W1[i];
    __syncthreads();
    gemm1_rpl(blockIdx.x - PB, G1A_ROWS, x, smem, G1);
    return;
  }
  int* cur = (int*)smem;
  int p = blockIdx.x;
  for (int i = t; i < NBUCK; i += FTPB) cur[i] = bstart[i] + H[p * NBUCK + i];
  __syncthreads();
  int f = *flag;
  int base = p * EPB;
  int i = t;
  for (; i + 3 * FTPB < EPB; i += 4 * FTPB) {
    int e0 = base + i, e1 = e0 + FTPB, e2 = e0 + 2 * FTPB, e3 = e0 + 3 * FTPB;
    int s0 = edge_at(ei, 0, e0, f), d0 = edge_at(ei, 1, e0, f);
    int s1 = edge_at(ei, 0, e1, f), d1 = edge_at(ei, 1, e1, f);
    int s2 = edge_at(ei, 0, e2, f), d2 = edge_at(ei, 1, e2, f);
    int s3 = edge_at(ei, 0, e3, f), d3 = edge_at(ei, 1, e3, f);
    int sl0 = atomicAdd(&cur[d0 >> BUCK_SHIFT], 1);
    int sl1 = atomicAdd(&cur[d1 >> BUCK_SHIFT], 1);
    int sl2 = atomicAdd(&cur[d2 >> BUCK_SHIFT], 1);
    int sl3 = atomicAdd(&cur[d3 >> BUCK_SHIFT], 1);
    sorted[sl0] = ((unsigned)s0 << BUCK_SHIFT) | (unsigned)(d0 & (BUCK_W - 1));
    sorted[sl1] = ((unsigned)s1 << BUCK_SHIFT) | (unsigned)(d1 & (BUCK_W - 1));
    sorted[sl2] = ((unsigned)s2 << BUCK_SHIFT) | (unsigned)(d2 & (BUCK_W - 1));
    sorted[sl3] = ((unsigned)s3 << BUCK_SHIFT) | (unsigned)(d3 & (BUCK_W - 1));
  }
  for (; i < EPB; i += FTPB) {
    int e = base + i;
    int s = edge_at(ei, 0, e, f);
    int d = edge_at(ei, 1, e, f);
    int slot = atomicAdd(&cur[d >> BUCK_SHIFT], 1);
    sorted[slot] = ((unsigned)s << BUCK_SHIFT) | (unsigned)(d & (BUCK_W - 1));
  }
}

// ---- sort pass 2: one block per bucket: LDS count + scan -> cnt/cursor/dinv + exact CSR,
//      then in-place dinv rescale of this bucket's G1 rows (vectorized uint4 = 8 bf16). ----
__global__ void __launch_bounds__(256) k_pass2(const unsigned* sorted, const int* bstart,
                                               int* cnt, int* cursor, float* dinv, int* csr,
                                               __hip_bfloat16* G1) {
  __shared__ unsigned se[SEG_CAP];
  __shared__ int scnt[BUCK_W], soff[BUCK_W], scur[BUCK_W];
  __shared__ float sdv[BUCK_W];
  int b = blockIdx.x, t = threadIdx.x;
  int s0 = bstart[b], s1 = bstart[b + 1], len = s1 - s0;
  for (int i = t; i < len && i < SEG_CAP; i += 256) se[i] = sorted[s0 + i];
  if (t < BUCK_W) scnt[t] = 0;
  __syncthreads();
  for (int i = t; i < len; i += 256) {
    unsigned u = (i < SEG_CAP) ? se[i] : sorted[s0 + i];
    atomicAdd(&scnt[u & (BUCK_W - 1)], 1);
  }
  __syncthreads();
  int c = (t < BUCK_W) ? scnt[t] : 0;
  if (t < BUCK_W) soff[t] = c;
  __syncthreads();
  for (int off = 1; off < BUCK_W; off <<= 1) {
    int u = 0;
    if (t >= off && t < BUCK_W) u = soff[t - off];
    __syncthreads();
    if (t < BUCK_W) soff[t] += u;
    __syncthreads();
  }
  if (t < BUCK_W) {
    int ex = soff[t] - c;                    // exclusive local offset
    int node = (b << BUCK_SHIFT) + t;
    float dv = rsqrtf((float)(c + 1));
    sdv[t] = dv;
    if (node < N_NODES) {
      cnt[node] = c;
      cursor[node] = s0 + ex;
      dinv[node] = dv;
    }
    scur[t] = ex;                            // running cursor starts at exclusive offset
  }
  __syncthreads();
  for (int i = t; i < len; i += 256) {
    unsigned u = (i < SEG_CAP) ? se[i] : sorted[s0 + i];
    int dl = u & (BUCK_W - 1);
    int r = atomicAdd(&scur[dl], 1);
    csr[s0 + r] = (int)(u >> BUCK_SHIFT);
  }
  // ---- in-place G1 rescale for this bucket's nodes (G1 written unscaled by f1/f2) ----
  int nbase = b << BUCK_SHIFT;
  int nlim = min(BUCK_W, N_NODES - nbase);   // nodes in this bucket
  uint4* Gv = (uint4*)(G1 + (size_t)nbase * 32);
  for (int q = t; q < nlim * 4; q += 256) {  // 4 uint4 (8 bf16 each) per 32-col row
    float sc = sdv[q >> 2];
    uint4 u = Gv[q];
    u.x = sc2(u.x, sc); u.y = sc2(u.y, sc);
    u.z = sc2(u.z, sc); u.w = sc2(u.w, sc);
    Gv[q] = u;
  }
}

// ---- plain count (fallback path) ----
__global__ void k_count(const int* ei, const int* flag, int* cnt) {
  int e = blockIdx.x * blockDim.x + threadIdx.x;
  if (e >= N_EDGES) return;
  int f = *flag;
  atomicAdd(&cnt[edge_at(ei, 1, e, f)], 1);
}

// ---- dinv (fallback path) ----
__global__ void k_dinv(const int* cnt, float* dinv) {
  int t = blockIdx.x * blockDim.x + threadIdx.x;
  if (t < N_NODES) dinv[t] = rsqrtf((float)(cnt[t] + 1));
}

// ---- FUSED agg1 + gemm2: gather pre-scaled G1 -> h in reg ->
//      G2[n,j] = (sum_k shfl(h,k)*W2[k,j]) * dinv[n], bf16 out.
//      16-deep gather unroll: all row loads issued before accumulation (MLP). ----
__global__ void __launch_bounds__(256) k_agg1f(const __hip_bfloat16* G, const int* cursor,
                                               const int* cnt, const int* csr, const float* dinv,
                                               const float* b1, const float* W2,
                                               __hip_bfloat16* G2) {
  int j = threadIdx.x & 31, g = threadIdx.x >> 5;
  int n = blockIdx.x * 8 + g;
  if (n >= N_NODES) return;
  int len = cnt[n];
  int st = cursor[n];
  float dn = dinv[n];
  float acc = bf2f(G[n * 32 + j]);        // self loop (pre-scaled)
  int i = 0;
  for (; i + 16 <= len; i += 16) {
    int s[16];
    #pragma unroll
    for (int q = 0; q < 16; q++) s[q] = csr[st + i + q];
    float v[16];
    #pragma unroll
    for (int q = 0; q < 16; q++) v[q] = bf2f(G[s[q] * 32 + j]);
    #pragma unroll
    for (int q = 0; q < 16; q++) acc += v[q];
  }
  for (; i + 4 <= len; i += 4) {
    int s[4];
    #pragma unroll
    for (int q = 0; q < 4; q++) s[q] = csr[st + i + q];
    float v[4];
    #pragma unroll
    for (int q = 0; q < 4; q++) v[q] = bf2f(G[s[q] * 32 + j]);
    #pragma unroll
    for (int q = 0; q < 4; q++) acc += v[q];
  }
  for (; i < len; i++) acc += bf2f(G[csr[st + i] * 32 + j]);
  float h = fmaxf(dn * acc + b1[j], 0.0f);
  float g2 = 0.0f;
  #pragma unroll
  for (int k = 0; k < HID; k++) {
    float wk = (j < NCLUS) ? W2[k * NCLUS + j] : 0.0f;   // L1-hot after first group
    g2 += __shfl(h, k, 32) * wk;
  }
  G2[n * 32 + j] = __float2bfloat16((j < NCLUS) ? g2 * dn : 0.0f);
}

// ---- CSR agg layer2 (pre-scaled G2), 16-deep gather + softmax -> out + fx8
//      + FUSED colsum: accumulate log1p(-fx^2) in-register (fx never re-read).
//      NOTE: 12500 blocks * 8 = 100000 nodes exact -> no early return, sync-safe. ----
__global__ void __launch_bounds__(256) k_agg2c(const __hip_bfloat16* G, const int* cursor,
                                               const int* cnt, const int* csr, const float* dinv,
                                               const float* b2, float* outp, unsigned char* fx8,
                                               float* colsum) {
  __shared__ float sd[256];
  int j = threadIdx.x & 31, g = threadIdx.x >> 5;
  int n = blockIdx.x * 8 + g;            // always < N_NODES (exact grid)
  int len = cnt[n];
  int st = cursor[n];
  float acc = bf2f(G[n * 32 + j]);
  int i = 0;
  for (; i + 16 <= len; i += 16) {
    int s[16];
    #pragma unroll
    for (int q = 0; q < 16; q++) s[q] = csr[st + i + q];
    float v[16];
    #pragma unroll
    for (int q = 0; q < 16; q++) v[q] = bf2f(G[s[q] * 32 + j]);
    #pragma unroll
    for (int q = 0; q < 16; q++) acc += v[q];
  }
  for (; i + 4 <= len; i += 4) {
    int s[4];
    #pragma unroll
    for (int q = 0; q < 4; q++) s[q] = csr[st + i + q];
    float v[4];
    #pragma unroll
    for (int q = 0; q < 4; q++) v[q] = bf2f(G[s[q] * 32 + j]);
    #pragma unroll
    for (int q = 0; q < 4; q++) acc += v[q];
  }
  for (; i < len; i++) acc += bf2f(G[csr[st + i] * 32 + j]);
  bool act = (j < NCLUS);
  float logit = act ? fminf(fmaxf(dinv[n] * acc + b2[j], -80.0f), 80.0f) : -1e30f;
  float m = logit;
  #pragma unroll
  for (int mask = 16; mask > 0; mask >>= 1) m = fmaxf(m, __shfl_xor(m, mask, 32));
  float ex = act ? __expf(logit - m) : 0.0f;
  float ssum = ex;
  #pragma unroll
  for (int mask = 16; mask > 0; mask >>= 1) ssum += __shfl_xor(ssum, mask, 32);
  float fx = ex / fmaxf(ssum, 1e-30f);
  if (act) outp[n * NCLUS + j] = fx;
  fx8[n * 32 + j] = enc8(act ? fx : 0.0f);
  // fused colsum: per-lane partial, block-reduce over the 8 node-groups
  sd[threadIdx.x] = act ? log1pf(-fx * fx) : 0.0f;
  __syncthreads();
  if (threadIdx.x < 32) {
    float s = 0.0f;
    #pragma unroll
    for (int gg = 0; gg < 8; gg++) s += sd[threadIdx.x + 32 * gg];
    if (threadIdx.x < NCLUS) atomicAdd(&colsum[threadIdx.x], s);
  }
}

// ---- fallback fp32 kernels (atomic path) ----
__global__ void __launch_bounds__(256) k_gemm1s(const float* x, const float* W1,
                                                const float* dinv, float* G1) {
  __shared__ float Ws[IN_DIM * HID];
  int tid = threadIdx.x;
  for (int i = tid; i < IN_DIM * HID; i += 256) Ws[i] = W1[i];
  __syncthreads();
  int j = tid & 31, r = tid >> 5;
  int n = blockIdx.x * 8 + r;
  if (n >= N_NODES) return;
  const float* xr = x + (size_t)n * IN_DIM;
  float acc = 0.0f;
  #pragma unroll
  for (int k = 0; k < IN_DIM; k++) acc += xr[k] * Ws[k * HID + j];
  G1[n * 32 + j] = acc * dinv[n];
}

__global__ void __launch_bounds__(256) k_gemm2s(const float* h, const float* W2,
                                                const float* dinv, float* G2) {
  __shared__ float Ws[HID * 32];
  int tid = threadIdx.x;
  for (int i = tid; i < HID * 32; i += 256) Ws[i] = 0.0f;
  __syncthreads();
  for (int i = tid; i < HID * NCLUS; i += 256) {
    int k = i / NCLUS, j = i % NCLUS;
    Ws[k * 32 + j] = W2[i];
  }
  __syncthreads();
  int j = tid & 31, r = tid >> 5;
  int n = blockIdx.x * 8 + r;
  if (n >= N_NODES) return;
  const float* hr = h + (size_t)n * 32;
  float acc = 0.0f;
  #pragma unroll
  for (int k = 0; k < HID; k++) acc += hr[k] * Ws[k * 32 + j];
  G2[n * 32 + j] = (j < NCLUS) ? acc * dinv[n] : 0.0f;
}

__global__ void __launch_bounds__(256) k_eagg2(const int* ei, const int* flag,
                                               const float* G, float* D) {
  int j = threadIdx.x & 31, g = threadIdx.x >> 5;
  int f = *flag;
  for (int e = blockIdx.x * 8 + g; e < N_EDGES; e += gridDim.x * 8) {
    int s = edge_at(ei, 0, e, f);
    int d = edge_at(ei, 1, e, f);
    atomicAdd(&D[d * 32 + j], G[s * 32 + j]);
  }
}

__global__ void k_relu2(const float* A, const float* dinv, const float* b1, float* G) {
  int t = blockIdx.x * blockDim.x + threadIdx.x;
  if (t >= N_NODES * 32) return;
  int n = t >> 5, j = t & 31;
  G[t] = fmaxf(dinv[n] * (A[t] + G[t]) + b1[j], 0.0f);
}

__global__ void __launch_bounds__(256) k_softmax2(const float* S, const float* G2, const float* dinv,
                                                  const float* b2, float* outp) {
  int n = blockIdx.x * blockDim.x + threadIdx.x;
  if (n >= N_NODES) return;
  float di = dinv[n];
  float lg[NCLUS];
  float m = -1e30f;
  #pragma unroll
  for (int j = 0; j < NCLUS; j++) {
    float v = di * (S[n * 32 + j] + G2[n * 32 + j]) + b2[j];
    v = fminf(fmaxf(v, -80.0f), 80.0f);
    lg[j] = v; m = fmaxf(m, v);
  }
  float ssum = 0.0f;
  #pragma unroll
  for (int j = 0; j < NCLUS; j++) { lg[j] = __expf(lg[j] - m); ssum += lg[j]; }
  float inv = 1.0f / ssum;
  #pragma unroll
  for (int j = 0; j < NCLUS; j++) outp[n * NCLUS + j] = lg[j] * inv;
}

// ---- out (fp32, stride 30) -> fx8 (fp8, stride 32), fallback path ----
__global__ void k_fx8(const float* outp, unsigned char* fx8) {
  int t = blockIdx.x * blockDim.x + threadIdx.x;
  if (t >= N_NODES * 32) return;
  int n = t >> 5, j = t & 31;
  fx8[t] = enc8((j < NCLUS) ? outp[n * NCLUS + j] : 0.0f);
}

// ---- edge MSE v5: standalone, 4 edges/thread EXACT (3125*256*4 = 3.2M, no guards),
//      all loads issued before compute, packed HW cvt ----
__global__ void __launch_bounds__(256) k_msee(const int* ei, const float* ep,
                                              const uint4* fx8, const int* flag,
                                              double* msed) {
  int f = *flag;
  int t = threadIdx.x;
  int tid = blockIdx.x * 256 + t;
  int e0 = tid, e1 = tid + MSE_S, e2 = tid + 2 * MSE_S, e3 = tid + 3 * MSE_S;  // all < N_EDGES
  // level 1: all edge-index + ep loads
  int s0 = edge_at(ei, 0, e0, f), d0 = edge_at(ei, 1, e0, f);
  int s1 = edge_at(ei, 0, e1, f), d1 = edge_at(ei, 1, e1, f);
  int s2 = edge_at(ei, 0, e2, f), d2 = edge_at(ei, 1, e2, f);
  int s3 = edge_at(ei, 0, e3, f), d3 = edge_at(ei, 1, e3, f);
  float p0 = ep[e0], p1 = ep[e1], p2 = ep[e2], p3 = ep[e3];
  // level 2: all row gathers (16 independent uint4 loads)
  uint4 a00 = fx8[s0*2], a01 = fx8[s0*2+1], b00 = fx8[d0*2], b01 = fx8[d0*2+1];
  uint4 a10 = fx8[s1*2], a11 = fx8[s1*2+1], b10 = fx8[d1*2], b11 = fx8[d1*2+1];
  uint4 a20 = fx8[s2*2], a21 = fx8[s2*2+1], b20 = fx8[d2*2], b21 = fx8[d2*2+1];
  uint4 a30 = fx8[s3*2], a31 = fx8[s3*2+1], b30 = fx8[d3*2], b31 = fx8[d3*2+1];
  // compute
  float f0 = rowdot(a00, a01, b00, b01) - p0;
  float f1 = rowdot(a10, a11, b10, b11) - p1;
  float f2 = rowdot(a20, a21, b20, b21) - p2;
  float f3 = rowdot(a30, a31, b30, b31) - p3;
  float local = f0 * f0 + f1 * f1 + f2 * f2 + f3 * f3;
  __shared__ float sd[256];
  sd[t] = local; __syncthreads();
  for (int off = 128; off > 0; off >>= 1) {
    if (t < off) sd[t] += sd[t + off];
    __syncthreads();
  }
  if (t == 0) atomicAdd(msed, (double)sd[0]);
}

// ---- edge MSE (fallback grid-stride version) ----
__global__ void __launch_bounds__(256) k_msef3(const int* ei, const float* ep,
                                               const uint4* fx8, const int* flag,
                                               double* msed) {
  int f = *flag;
  int tid = blockIdx.x * blockDim.x + threadIdx.x;
  float local = 0.0f;
  for (int e = tid; e < N_EDGES; e += gridDim.x * blockDim.x) {
    int s = edge_at(ei, 0, e, f);
    int d = edge_at(ei, 1, e, f);
    const uint4* rs = fx8 + s * 2;
    const uint4* rd = fx8 + d * 2;
    uint4 a0 = rs[0], a1 = rs[1];
    uint4 b0 = rd[0], b1 = rd[1];
    float acc = rowdot(a0, a1, b0, b1);
    float diff = acc - ep[e];
    local += diff * diff;
  }
  __shared__ float sd[256];
  sd[threadIdx.x] = local; __syncthreads();
  for (int off = 128; off > 0; off >>= 1) {
    if (threadIdx.x < off) sd[threadIdx.x] += sd[threadIdx.x + off];
    __syncthreads();
  }
  if (threadIdx.x == 0) atomicAdd(msed, (double)sd[0]);
}

// ---- column sums of log(1-FX^2) (fallback path) ----
__global__ void __launch_bounds__(256) k_colsumf(const float* FX, float* colsum) {
  __shared__ float sd[256];
  int tid = threadIdx.x;
  int j = tid & 31, g = tid >> 5;
  float local = 0.0f;
  if (j < NCLUS) {
    for (int n = blockIdx.x * 8 + g; n < N_NODES; n += gridDim.x * 8) {
      float v = FX[n * NCLUS + j];
      local += log1pf(-v * v);
    }
  }
  sd[tid] = local; __syncthreads();
  if (tid < 32) {
    float s = 0.0f;
    #pragma unroll
    for (int gg = 0; gg < 8; gg++) s += sd[tid + 32 * gg];
    if (tid < NCLUS) atomicAdd(&colsum[tid], s);
  }
}

// ---- final loss ----
__global__ void k_final(const float* colsum, const double* msed, float* out) {
  int tid = threadIdx.x;
  float v = 0.0f;
  if (tid < NCLUS) v = logf(1.0001f - __expf(colsum[tid]));
  #pragma unroll
  for (int mask = 32; mask > 0; mask >>= 1) v += __shfl_xor(v, mask, 64);
  if (tid == 0) {
    float preg = -v;
    float msev = (float)(*msed / (double)N_EDGES);
    out[(size_t)N_NODES * NCLUS] = msev + 0.01f * preg;
  }
}

extern "C" void kernel_launch(void* const* d_in, const int* in_sizes, int n_in,
                              void* d_out, int out_size, void* d_ws, size_t ws_size,
                              hipStream_t stream) {
  const float* x  = (const float*)d_in[0];
  const int*   ei = (const int*)d_in[1];
  const float* ep = (const float*)d_in[2];
  const float* W1 = (const float*)d_in[3];
  const float* b1 = (const float*)d_in[4];
  const float* W2 = (const float*)d_in[5];
  const float* b2 = (const float*)d_in[6];
  float* out = (float*)d_out;   // fp32: FX[100000*30] then loss scalar

  char* ws = (char*)d_ws;
  size_t off = 0;
  auto alloc = [&](size_t bytes) { size_t o = off; off += (bytes + 255) & ~(size_t)255; return o; };

  size_t o_hdr  = alloc(1024);                       // flag@0, msed@8(double), colsum@256
  size_t o_cnt  = alloc((size_t)N_NODES * 4);
  size_t o_dinv = alloc((size_t)N_NODES * 4);
  size_t o_B1   = alloc((size_t)N_NODES * 32 * 4);   // CSR: G1 bf16 [0,6.4M) + H/tot/bstart [6.4M,...)
  size_t o_B2   = alloc((size_t)N_NODES * 32 * 4);   // CSR: sorted [0,12.8M) -> later fx8[0,3.2M)+G2[3.2M,9.6M)

  int*    flag   = (int*)(ws + o_hdr);
  double* msed   = (double*)(ws + o_hdr + 8);
  float*  colsum = (float*)(ws + o_hdr + 256);
  int*    cnt    = (int*)(ws + o_cnt);
  float*  dinv   = (float*)(ws + o_dinv);
  float*  B1f    = (float*)(ws + o_B1);
  float*  B2f    = (float*)(ws + o_B2);
  __hip_bfloat16* B1b = (__hip_bfloat16*)(ws + o_B1);
  unsigned char*  B2c = (unsigned char*)(ws + o_B2);

  const int nodeBlocks = (N_NODES + 255) / 256;
  const int edgeBlocks = EDGE_BLOCKS;
  const int grpBlocks  = GRP_BLOCKS;
  const int elemBlocks = (N_NODES * 32 + 255) / 256;

  k_detect<<<1, 64, 0, stream>>>((const unsigned int*)ei, flag, colsum, msed);

  size_t o_cursor = alloc((size_t)N_NODES * 4);
  size_t o_csr    = alloc((size_t)N_EDGES * 4);
  bool use_csr = (off <= ws_size);

  const unsigned char* fx8;

  if (use_csr) {
    int* cursor = (int*)(ws + o_cursor);
    int* csr    = (int*)(ws + o_csr);
    // overlays inside B1 upper half (G1 bf16 occupies [0, 6.4M))
    int* H      = (int*)(ws + o_B1 + 6400000);                 // 128*782*4 = 400KB
    int* tot    = (int*)(ws + o_B1 + 6400000 + 401408);        // 782*4
    int* bstart = (int*)(ws + o_B1 + 6400000 + 405504);        // 783*4
    unsigned* sorted = (unsigned*)B2c;                          // B2 [0,12.8M), dead after pass2

    __hip_bfloat16* G1b = B1b;

    // hist || gemmA -> scans -> scat1 || gemmB -> pass2 (+ G1 dinv rescale)
    k_f1<<<PB + G1A_BLK, FTPB, 0, stream>>>(ei, flag, H, x, W1, G1b);
    k_hscan<<<NBUCK, PB, 0, stream>>>(H, tot);
    k_bscan<<<1, 1024, 0, stream>>>(tot, bstart);
    k_f2<<<PB + G1B_BLK, FTPB, 0, stream>>>(ei, flag, H, bstart, sorted, x, W1, G1b);
    k_pass2<<<NBUCK, 256, 0, stream>>>(sorted, bstart, cnt, cursor, dinv, csr, G1b);

    __hip_bfloat16* G2b = (__hip_bfloat16*)(ws + o_B2 + (size_t)N_NODES * 32); // [3.2M,9.6M)
    unsigned char*  fx  = B2c;                                                  // [0,3.2M)

    k_agg1f<<<grpBlocks, 256, 0, stream>>>(G1b, cursor, cnt, csr, dinv, b1, W2, G2b);
    k_agg2c<<<grpBlocks, 256, 0, stream>>>(G2b, cursor, cnt, csr, dinv, b2, out, fx, colsum);
    fx8 = fx;

    // standalone exact-sized mse (colsum already folded into agg2c)
    k_msee<<<MSE_BLOCKS, 256, 0, stream>>>(ei, ep, (const uint4*)fx8, flag, msed);
  } else {
    k_zeroall<<<nodeBlocks, 256, 0, stream>>>(cnt, colsum, msed);
    k_count<<<edgeBlocks, 256, 0, stream>>>(ei, flag, cnt);
    k_dinv<<<nodeBlocks, 256, 0, stream>>>(cnt, dinv);
    k_gemm1s<<<grpBlocks, 256, 0, stream>>>(x, W1, dinv, B1f);
    hipMemsetAsync(B2f, 0, (size_t)N_NODES * 32 * 4, stream);
    k_eagg2<<<8192, 256, 0, stream>>>(ei, flag, B1f, B2f);
    k_relu2<<<elemBlocks, 256, 0, stream>>>(B2f, dinv, b1, B1f);
    k_gemm2s<<<grpBlocks, 256, 0, stream>>>(B1f, W2, dinv, B2f);
    hipMemsetAsync(B1f, 0, (size_t)N_NODES * 32 * 4, stream);
    k_eagg2<<<8192, 256, 0, stream>>>(ei, flag, B2f, B1f);
    k_softmax2<<<nodeBlocks, 256, 0, stream>>>(B1f, B2f, dinv, b2, out);
    k_fx8<<<elemBlocks, 256, 0, stream>>>(out, (unsigned char*)B1b);
    fx8 = (const unsigned char*)B1b;
    k_msef3<<<4096, 256, 0, stream>>>(ei, ep, (const uint4*)fx8, flag, msed);
    k_colsumf<<<256, 256, 0, stream>>>(out, colsum);
  }

  k_final<<<1, 64, 0, stream>>>(colsum, msed, out);
}

// Round 16
// 435.310 us; speedup vs baseline: 1.2264x; 1.2264x over previous
//
#include <hip/hip_runtime.h>
#include <hip/hip_bf16.h>
#include <hip/hip_fp8.h>

#define N_NODES 100000
#define N_EDGES 3200000
#define IN_DIM  128
#define HID     32
#define NCLUS   30
#define EDGE_BLOCKS 12500 // ceil(3200000/256)
#define GRP_BLOCKS  12500 // ceil(100000/8)

// ---- counting-sort geometry ----
#define BUCK_SHIFT 7
#define BUCK_W     128
#define NBUCK      782
#define PB         128                 // pass-1 blocks (128B per (block,bucket) run)
#define EPB        25000               // 128*25000 = 3.2M exact
#define SEG_CAP    8192
#define FTPB       512                 // threads per fused block

// ---- gemm1 row-per-lane geometry: 512 rows/block (lane owns a row; W1 in LDS) ----
#define G1A_BLK    98                  // 98*512 = 50176 rows in k_f1
#define G1A_ROWS   50176
#define G1B_BLK    98                  // rows [50176,100000) guarded, in k_f2

// ---- mse geometry: 3125*256*4 = 3.2M EXACT (no guards, standalone).
//      R15 lesson: do NOT fuse colsum into agg2c (barrier+LDS -> VGPR 32 -> 2x slower). ----
#define MSE_BLOCKS 3125
#define MSE_S      (MSE_BLOCKS * 256)  // 800000

__device__ __forceinline__ float bf2f(__hip_bfloat16 v) { return __bfloat162float(v); }

// fp8 e4m3 (OCP) encode/decode via HW cvt
__device__ __forceinline__ unsigned char enc8(float v) {
  __hip_fp8_e4m3 t(v); return (unsigned char)t.__x;
}
__device__ __forceinline__ float dec8(unsigned b) {
  __hip_fp8_e4m3 t; t.__x = (__hip_fp8_storage_t)b; return (float)t;
}
__device__ __forceinline__ float dot4_fp8(unsigned a, unsigned b) {
  float r = 0.0f;
  #pragma unroll
  for (int k = 0; k < 4; k++)
    r += dec8((a >> (8 * k)) & 0xffu) * dec8((b >> (8 * k)) & 0xffu);
  return r;
}

// packed dot of 4 fp8 pairs: HW packed cvt (2 floats/instr, OCP e4m3 on gfx950)
typedef float floatx2 __attribute__((ext_vector_type(2)));
__device__ __forceinline__ float dot4p(unsigned a, unsigned b) {
#if __has_builtin(__builtin_amdgcn_cvt_pk_f32_fp8)
  floatx2 al = __builtin_amdgcn_cvt_pk_f32_fp8((int)a, false);
  floatx2 ah = __builtin_amdgcn_cvt_pk_f32_fp8((int)a, true);
  floatx2 bl = __builtin_amdgcn_cvt_pk_f32_fp8((int)b, false);
  floatx2 bh = __builtin_amdgcn_cvt_pk_f32_fp8((int)b, true);
  return al[0]*bl[0] + al[1]*bl[1] + ah[0]*bh[0] + ah[1]*bh[1];
#else
  return dot4_fp8(a, b);
#endif
}
__device__ __forceinline__ float rowdot(const uint4& a0, const uint4& a1,
                                        const uint4& b0, const uint4& b1) {
  return dot4p(a0.x, b0.x) + dot4p(a0.y, b0.y) + dot4p(a0.z, b0.z) + dot4p(a0.w, b0.w)
       + dot4p(a1.x, b1.x) + dot4p(a1.y, b1.y) + dot4p(a1.z, b1.z) + dot4p(a1.w, b1.w);
}

// scale a packed pair of bf16 by sc (RNE via __float2bfloat16)
__device__ __forceinline__ unsigned sc2(unsigned u, float sc) {
  __hip_bfloat16 h0 = *reinterpret_cast<__hip_bfloat16*>(&u);
  unsigned uh = u >> 16;
  __hip_bfloat16 h1 = *reinterpret_cast<__hip_bfloat16*>(&uh);
  __hip_bfloat16 r0 = __float2bfloat16(__bfloat162float(h0) * sc);
  __hip_bfloat16 r1 = __float2bfloat16(__bfloat162float(h1) * sc);
  unsigned a = *reinterpret_cast<unsigned short*>(&r0);
  unsigned b = *reinterpret_cast<unsigned short*>(&r1);
  return a | (b << 16);
}

// edge_index accessor: f=0 -> int32 layout, f=1 -> int64 layout (read low word)
__device__ __forceinline__ int edge_at(const int* ei, int row, int e, int f) {
  int v = ei[(row * N_EDGES + e) << f];
  return min(max(v, 0), N_NODES - 1);
}

// ---- detect int32 vs int64 edge_index + zero loss scalars ----
__global__ void k_detect(const unsigned int* ei, int* flag, float* colsum, double* msed) {
  int t = threadIdx.x;
  if (t < 32) colsum[t] = 0.0f;
  if (t == 32) *msed = 0.0;
  if (t == 0) {
    int zeros = 0;
    for (int i = 1; i < 128; i += 2) zeros += (ei[i] == 0u) ? 1 : 0;
    *flag = (zeros >= 48) ? 1 : 0;
  }
}

// ---- zero cnt + loss scalars (fallback path) ----
__global__ void k_zeroall(int* cnt, float* colsum, double* msed) {
  int t = blockIdx.x * blockDim.x + threadIdx.x;
  if (t < N_NODES) cnt[t] = 0;
  if (t < 32) colsum[t] = 0.0f;
  if (t == 32) *msed = 0.0;
}

// ---- GEMM1 row-per-lane body: lane owns row n; x per-lane float4 (distinct lines),
//      W1 broadcast from LDS. UNSCALED bf16 out (dinv applied in k_pass2 rescale). ----
__device__ __forceinline__ void gemm1_rpl(int gb, int row_off, const float* x,
                                          const float* Wl, __hip_bfloat16* G1) {
  int n = row_off + gb * FTPB + threadIdx.x;
  if (n >= N_NODES) return;
  float acc[32];
  #pragma unroll
  for (int j = 0; j < 32; j++) acc[j] = 0.0f;
  const float4* xp = (const float4*)(x + (size_t)n * IN_DIM);
  #pragma unroll
  for (int kc = 0; kc < 4; kc++) {          // 4 chunks of 32 k
    float4 xv[8];
    #pragma unroll
    for (int q = 0; q < 8; q++) xv[q] = xp[kc * 8 + q];
    #pragma unroll
    for (int q = 0; q < 8; q++) {
      #pragma unroll
      for (int e = 0; e < 4; e++) {
        float xk = (e == 0) ? xv[q].x : (e == 1) ? xv[q].y : (e == 2) ? xv[q].z : xv[q].w;
        const float4* wr = (const float4*)(Wl + (kc * 32 + q * 4 + e) * HID);
        #pragma unroll
        for (int jv = 0; jv < 8; jv++) {    // 8 x float4 = 32 cols
          float4 w4 = wr[jv];               // uniform addr -> LDS broadcast
          acc[4*jv+0] += xk * w4.x;
          acc[4*jv+1] += xk * w4.y;
          acc[4*jv+2] += xk * w4.z;
          acc[4*jv+3] += xk * w4.w;
        }
      }
    }
  }
  unsigned pk[16];
  #pragma unroll
  for (int jp = 0; jp < 16; jp++) {
    __hip_bfloat16 l0 = __float2bfloat16(acc[2*jp]);
    __hip_bfloat16 l1 = __float2bfloat16(acc[2*jp+1]);
    unsigned a = *reinterpret_cast<unsigned short*>(&l0);
    unsigned b = *reinterpret_cast<unsigned short*>(&l1);
    pk[jp] = a | (b << 16);
  }
  uint4* dst = (uint4*)(G1 + (size_t)n * 32);   // 64B = lane-owned line
  dst[0] = make_uint4(pk[0], pk[1], pk[2], pk[3]);
  dst[1] = make_uint4(pk[4], pk[5], pk[6], pk[7]);
  dst[2] = make_uint4(pk[8], pk[9], pk[10], pk[11]);
  dst[3] = make_uint4(pk[12], pk[13], pk[14], pk[15]);
}

// ---- FUSED 1: blocks [0,PB) = LDS bucket histogram (4-deep prefetch); rest = gemmA ----
__global__ void __launch_bounds__(FTPB) k_f1(const int* ei, const int* flag, int* H,
                                             const float* x, const float* W1, __hip_bfloat16* G1) {
  __shared__ float smem[IN_DIM * HID];           // 16KB: Wl for gemm / h[] for hist
  int t = threadIdx.x;
  if (blockIdx.x >= PB) {
    for (int i = t; i < IN_DIM * HID; i += FTPB) smem[i] = W1[i];
    __syncthreads();
    gemm1_rpl(blockIdx.x - PB, 0, x, smem, G1);
    return;
  }
  int* h = (int*)smem;
  int p = blockIdx.x;
  for (int i = t; i < NBUCK; i += FTPB) h[i] = 0;
  __syncthreads();
  int f = *flag;
  int base = p * EPB;
  int i = t;
  for (; i + 3 * FTPB < EPB; i += 4 * FTPB) {
    int d0 = edge_at(ei, 1, base + i,            f);
    int d1 = edge_at(ei, 1, base + i + FTPB,     f);
    int d2 = edge_at(ei, 1, base + i + 2 * FTPB, f);
    int d3 = edge_at(ei, 1, base + i + 3 * FTPB, f);
    atomicAdd(&h[d0 >> BUCK_SHIFT], 1);
    atomicAdd(&h[d1 >> BUCK_SHIFT], 1);
    atomicAdd(&h[d2 >> BUCK_SHIFT], 1);
    atomicAdd(&h[d3 >> BUCK_SHIFT], 1);
  }
  for (; i < EPB; i += FTPB) {
    int d = edge_at(ei, 1, base + i, f);
    atomicAdd(&h[d >> BUCK_SHIFT], 1);
  }
  __syncthreads();
  for (int q = t; q < NBUCK; q += FTPB) H[p * NBUCK + q] = h[q];
}

// ---- sort scan A: column-scan of H over PB blocks -> exclusive in place + bucket totals ----
__global__ void __launch_bounds__(PB) k_hscan(int* H, int* tot) {
  __shared__ int s[PB];
  int b = blockIdx.x, t = threadIdx.x;
  int v = H[t * NBUCK + b];
  s[t] = v; __syncthreads();
  for (int off = 1; off < PB; off <<= 1) {
    int u = (t >= off) ? s[t - off] : 0;
    __syncthreads();
    s[t] += u;
    __syncthreads();
  }
  H[t * NBUCK + b] = s[t] - v;               // exclusive prefix within bucket column
  if (t == PB - 1) tot[b] = s[t];
}

// ---- sort scan B: exclusive scan of bucket totals -> bstart[0..NBUCK] ----
__global__ void __launch_bounds__(1024) k_bscan(const int* tot, int* bstart) {
  __shared__ int s[1024];
  int t = threadIdx.x;
  int v = (t < NBUCK) ? tot[t] : 0;
  s[t] = v; __syncthreads();
  for (int off = 1; off < 1024; off <<= 1) {
    int u = (t >= off) ? s[t - off] : 0;
    __syncthreads();
    s[t] += u;
    __syncthreads();
  }
  if (t < NBUCK) bstart[t] = s[t] - v;
  if (t == NBUCK - 1) bstart[NBUCK] = s[t];  // = N_EDGES
}

// ---- FUSED 2: blocks [0,PB) = scatter (4-deep prefetch); rest = gemmB ----
__global__ void __launch_bounds__(FTPB) k_f2(const int* ei, const int* flag, const int* H,
                                             const int* bstart, unsigned* sorted,
                                             const float* x, const float* W1, __hip_bfloat16* G1) {
  __shared__ float smem[IN_DIM * HID];           // 16KB: Wl for gemm / cur[] for scatter
  int t = threadIdx.x;
  if (blockIdx.x >= PB) {
    for (int i = t; i < IN_DIM * HID; i += FTPB) smem[i] = W1[i];
    __syncthreads();
    gemm1_rpl(blockIdx.x - PB, G1A_ROWS, x, smem, G1);
    return;
  }
  int* cur = (int*)smem;
  int p = blockIdx.x;
  for (int i = t; i < NBUCK; i += FTPB) cur[i] = bstart[i] + H[p * NBUCK + i];
  __syncthreads();
  int f = *flag;
  int base = p * EPB;
  int i = t;
  for (; i + 3 * FTPB < EPB; i += 4 * FTPB) {
    int e0 = base + i, e1 = e0 + FTPB, e2 = e0 + 2 * FTPB, e3 = e0 + 3 * FTPB;
    int s0 = edge_at(ei, 0, e0, f), d0 = edge_at(ei, 1, e0, f);
    int s1 = edge_at(ei, 0, e1, f), d1 = edge_at(ei, 1, e1, f);
    int s2 = edge_at(ei, 0, e2, f), d2 = edge_at(ei, 1, e2, f);
    int s3 = edge_at(ei, 0, e3, f), d3 = edge_at(ei, 1, e3, f);
    int sl0 = atomicAdd(&cur[d0 >> BUCK_SHIFT], 1);
    int sl1 = atomicAdd(&cur[d1 >> BUCK_SHIFT], 1);
    int sl2 = atomicAdd(&cur[d2 >> BUCK_SHIFT], 1);
    int sl3 = atomicAdd(&cur[d3 >> BUCK_SHIFT], 1);
    sorted[sl0] = ((unsigned)s0 << BUCK_SHIFT) | (unsigned)(d0 & (BUCK_W - 1));
    sorted[sl1] = ((unsigned)s1 << BUCK_SHIFT) | (unsigned)(d1 & (BUCK_W - 1));
    sorted[sl2] = ((unsigned)s2 << BUCK_SHIFT) | (unsigned)(d2 & (BUCK_W - 1));
    sorted[sl3] = ((unsigned)s3 << BUCK_SHIFT) | (unsigned)(d3 & (BUCK_W - 1));
  }
  for (; i < EPB; i += FTPB) {
    int e = base + i;
    int s = edge_at(ei, 0, e, f);
    int d = edge_at(ei, 1, e, f);
    int slot = atomicAdd(&cur[d >> BUCK_SHIFT], 1);
    sorted[slot] = ((unsigned)s << BUCK_SHIFT) | (unsigned)(d & (BUCK_W - 1));
  }
}

// ---- sort pass 2: one block per bucket: LDS count + scan -> cnt/cursor/dinv + exact CSR,
//      then in-place dinv rescale of this bucket's G1 rows (vectorized uint4 = 8 bf16). ----
__global__ void __launch_bounds__(256) k_pass2(const unsigned* sorted, const int* bstart,
                                               int* cnt, int* cursor, float* dinv, int* csr,
                                               __hip_bfloat16* G1) {
  __shared__ unsigned se[SEG_CAP];
  __shared__ int scnt[BUCK_W], soff[BUCK_W], scur[BUCK_W];
  __shared__ float sdv[BUCK_W];
  int b = blockIdx.x, t = threadIdx.x;
  int s0 = bstart[b], s1 = bstart[b + 1], len = s1 - s0;
  for (int i = t; i < len && i < SEG_CAP; i += 256) se[i] = sorted[s0 + i];
  if (t < BUCK_W) scnt[t] = 0;
  __syncthreads();
  for (int i = t; i < len; i += 256) {
    unsigned u = (i < SEG_CAP) ? se[i] : sorted[s0 + i];
    atomicAdd(&scnt[u & (BUCK_W - 1)], 1);
  }
  __syncthreads();
  int c = (t < BUCK_W) ? scnt[t] : 0;
  if (t < BUCK_W) soff[t] = c;
  __syncthreads();
  for (int off = 1; off < BUCK_W; off <<= 1) {
    int u = 0;
    if (t >= off && t < BUCK_W) u = soff[t - off];
    __syncthreads();
    if (t < BUCK_W) soff[t] += u;
    __syncthreads();
  }
  if (t < BUCK_W) {
    int ex = soff[t] - c;                    // exclusive local offset
    int node = (b << BUCK_SHIFT) + t;
    float dv = rsqrtf((float)(c + 1));
    sdv[t] = dv;
    if (node < N_NODES) {
      cnt[node] = c;
      cursor[node] = s0 + ex;
      dinv[node] = dv;
    }
    scur[t] = ex;                            // running cursor starts at exclusive offset
  }
  __syncthreads();
  for (int i = t; i < len; i += 256) {
    unsigned u = (i < SEG_CAP) ? se[i] : sorted[s0 + i];
    int dl = u & (BUCK_W - 1);
    int r = atomicAdd(&scur[dl], 1);
    csr[s0 + r] = (int)(u >> BUCK_SHIFT);
  }
  // ---- in-place G1 rescale for this bucket's nodes (G1 written unscaled by f1/f2) ----
  int nbase = b << BUCK_SHIFT;
  int nlim = min(BUCK_W, N_NODES - nbase);   // nodes in this bucket
  uint4* Gv = (uint4*)(G1 + (size_t)nbase * 32);
  for (int q = t; q < nlim * 4; q += 256) {  // 4 uint4 (8 bf16 each) per 32-col row
    float sc = sdv[q >> 2];
    uint4 u = Gv[q];
    u.x = sc2(u.x, sc); u.y = sc2(u.y, sc);
    u.z = sc2(u.z, sc); u.w = sc2(u.w, sc);
    Gv[q] = u;
  }
}

// ---- plain count (fallback path) ----
__global__ void k_count(const int* ei, const int* flag, int* cnt) {
  int e = blockIdx.x * blockDim.x + threadIdx.x;
  if (e >= N_EDGES) return;
  int f = *flag;
  atomicAdd(&cnt[edge_at(ei, 1, e, f)], 1);
}

// ---- dinv (fallback path) ----
__global__ void k_dinv(const int* cnt, float* dinv) {
  int t = blockIdx.x * blockDim.x + threadIdx.x;
  if (t < N_NODES) dinv[t] = rsqrtf((float)(cnt[t] + 1));
}

// ---- FUSED agg1 + gemm2: gather pre-scaled G1 -> h in reg ->
//      G2[n,j] = (sum_k shfl(h,k)*W2[k,j]) * dinv[n], bf16 out.
//      16-deep gather unroll: all row loads issued before accumulation (MLP). ----
__global__ void __launch_bounds__(256) k_agg1f(const __hip_bfloat16* G, const int* cursor,
                                               const int* cnt, const int* csr, const float* dinv,
                                               const float* b1, const float* W2,
                                               __hip_bfloat16* G2) {
  int j = threadIdx.x & 31, g = threadIdx.x >> 5;
  int n = blockIdx.x * 8 + g;
  if (n >= N_NODES) return;
  int len = cnt[n];
  int st = cursor[n];
  float dn = dinv[n];
  float acc = bf2f(G[n * 32 + j]);        // self loop (pre-scaled)
  int i = 0;
  for (; i + 16 <= len; i += 16) {
    int s[16];
    #pragma unroll
    for (int q = 0; q < 16; q++) s[q] = csr[st + i + q];
    float v[16];
    #pragma unroll
    for (int q = 0; q < 16; q++) v[q] = bf2f(G[s[q] * 32 + j]);
    #pragma unroll
    for (int q = 0; q < 16; q++) acc += v[q];
  }
  for (; i + 4 <= len; i += 4) {
    int s[4];
    #pragma unroll
    for (int q = 0; q < 4; q++) s[q] = csr[st + i + q];
    float v[4];
    #pragma unroll
    for (int q = 0; q < 4; q++) v[q] = bf2f(G[s[q] * 32 + j]);
    #pragma unroll
    for (int q = 0; q < 4; q++) acc += v[q];
  }
  for (; i < len; i++) acc += bf2f(G[csr[st + i] * 32 + j]);
  float h = fmaxf(dn * acc + b1[j], 0.0f);
  float g2 = 0.0f;
  #pragma unroll
  for (int k = 0; k < HID; k++) {
    float wk = (j < NCLUS) ? W2[k * NCLUS + j] : 0.0f;   // L1-hot after first group
    g2 += __shfl(h, k, 32) * wk;
  }
  G2[n * 32 + j] = __float2bfloat16((j < NCLUS) ? g2 * dn : 0.0f);
}

// ---- CSR agg layer2 (pre-scaled G2), 16-deep gather + softmax -> out + fx8.
//      NO colsum fusion (R15: barrier+LDS here -> VGPR 32 -> gather serialized, 2x). ----
__global__ void __launch_bounds__(256) k_agg2c(const __hip_bfloat16* G, const int* cursor,
                                               const int* cnt, const int* csr, const float* dinv,
                                               const float* b2, float* outp, unsigned char* fx8) {
  int j = threadIdx.x & 31, g = threadIdx.x >> 5;
  int n = blockIdx.x * 8 + g;
  if (n >= N_NODES) return;
  int len = cnt[n];
  int st = cursor[n];
  float acc = bf2f(G[n * 32 + j]);
  int i = 0;
  for (; i + 16 <= len; i += 16) {
    int s[16];
    #pragma unroll
    for (int q = 0; q < 16; q++) s[q] = csr[st + i + q];
    float v[16];
    #pragma unroll
    for (int q = 0; q < 16; q++) v[q] = bf2f(G[s[q] * 32 + j]);
    #pragma unroll
    for (int q = 0; q < 16; q++) acc += v[q];
  }
  for (; i + 4 <= len; i += 4) {
    int s[4];
    #pragma unroll
    for (int q = 0; q < 4; q++) s[q] = csr[st + i + q];
    float v[4];
    #pragma unroll
    for (int q = 0; q < 4; q++) v[q] = bf2f(G[s[q] * 32 + j]);
    #pragma unroll
    for (int q = 0; q < 4; q++) acc += v[q];
  }
  for (; i < len; i++) acc += bf2f(G[csr[st + i] * 32 + j]);
  bool act = (j < NCLUS);
  float logit = act ? fminf(fmaxf(dinv[n] * acc + b2[j], -80.0f), 80.0f) : -1e30f;
  float m = logit;
  #pragma unroll
  for (int mask = 16; mask > 0; mask >>= 1) m = fmaxf(m, __shfl_xor(m, mask, 32));
  float ex = act ? __expf(logit - m) : 0.0f;
  float ssum = ex;
  #pragma unroll
  for (int mask = 16; mask > 0; mask >>= 1) ssum += __shfl_xor(ssum, mask, 32);
  float fx = ex / fmaxf(ssum, 1e-30f);
  if (act) outp[n * NCLUS + j] = fx;
  fx8[n * 32 + j] = enc8(act ? fx : 0.0f);
}

// ---- fallback fp32 kernels (atomic path) ----
__global__ void __launch_bounds__(256) k_gemm1s(const float* x, const float* W1,
                                                const float* dinv, float* G1) {
  __shared__ float Ws[IN_DIM * HID];
  int tid = threadIdx.x;
  for (int i = tid; i < IN_DIM * HID; i += 256) Ws[i] = W1[i];
  __syncthreads();
  int j = tid & 31, r = tid >> 5;
  int n = blockIdx.x * 8 + r;
  if (n >= N_NODES) return;
  const float* xr = x + (size_t)n * IN_DIM;
  float acc = 0.0f;
  #pragma unroll
  for (int k = 0; k < IN_DIM; k++) acc += xr[k] * Ws[k * HID + j];
  G1[n * 32 + j] = acc * dinv[n];
}

__global__ void __launch_bounds__(256) k_gemm2s(const float* h, const float* W2,
                                                const float* dinv, float* G2) {
  __shared__ float Ws[HID * 32];
  int tid = threadIdx.x;
  for (int i = tid; i < HID * 32; i += 256) Ws[i] = 0.0f;
  __syncthreads();
  for (int i = tid; i < HID * NCLUS; i += 256) {
    int k = i / NCLUS, j = i % NCLUS;
    Ws[k * 32 + j] = W2[i];
  }
  __syncthreads();
  int j = tid & 31, r = tid >> 5;
  int n = blockIdx.x * 8 + r;
  if (n >= N_NODES) return;
  const float* hr = h + (size_t)n * 32;
  float acc = 0.0f;
  #pragma unroll
  for (int k = 0; k < HID; k++) acc += hr[k] * Ws[k * 32 + j];
  G2[n * 32 + j] = (j < NCLUS) ? acc * dinv[n] : 0.0f;
}

__global__ void __launch_bounds__(256) k_eagg2(const int* ei, const int* flag,
                                               const float* G, float* D) {
  int j = threadIdx.x & 31, g = threadIdx.x >> 5;
  int f = *flag;
  for (int e = blockIdx.x * 8 + g; e < N_EDGES; e += gridDim.x * 8) {
    int s = edge_at(ei, 0, e, f);
    int d = edge_at(ei, 1, e, f);
    atomicAdd(&D[d * 32 + j], G[s * 32 + j]);
  }
}

__global__ void k_relu2(const float* A, const float* dinv, const float* b1, float* G) {
  int t = blockIdx.x * blockDim.x + threadIdx.x;
  if (t >= N_NODES * 32) return;
  int n = t >> 5, j = t & 31;
  G[t] = fmaxf(dinv[n] * (A[t] + G[t]) + b1[j], 0.0f);
}

__global__ void __launch_bounds__(256) k_softmax2(const float* S, const float* G2, const float* dinv,
                                                  const float* b2, float* outp) {
  int n = blockIdx.x * blockDim.x + threadIdx.x;
  if (n >= N_NODES) return;
  float di = dinv[n];
  float lg[NCLUS];
  float m = -1e30f;
  #pragma unroll
  for (int j = 0; j < NCLUS; j++) {
    float v = di * (S[n * 32 + j] + G2[n * 32 + j]) + b2[j];
    v = fminf(fmaxf(v, -80.0f), 80.0f);
    lg[j] = v; m = fmaxf(m, v);
  }
  float ssum = 0.0f;
  #pragma unroll
  for (int j = 0; j < NCLUS; j++) { lg[j] = __expf(lg[j] - m); ssum += lg[j]; }
  float inv = 1.0f / ssum;
  #pragma unroll
  for (int j = 0; j < NCLUS; j++) outp[n * NCLUS + j] = lg[j] * inv;
}

// ---- out (fp32, stride 30) -> fx8 (fp8, stride 32), fallback path ----
__global__ void k_fx8(const float* outp, unsigned char* fx8) {
  int t = blockIdx.x * blockDim.x + threadIdx.x;
  if (t >= N_NODES * 32) return;
  int n = t >> 5, j = t & 31;
  fx8[t] = enc8((j < NCLUS) ? outp[n * NCLUS + j] : 0.0f);
}

// ---- edge MSE v5: standalone, 4 edges/thread EXACT (3125*256*4 = 3.2M, no guards),
//      all loads issued before compute, packed HW cvt ----
__global__ void __launch_bounds__(256) k_msee(const int* ei, const float* ep,
                                              const uint4* fx8, const int* flag,
                                              double* msed) {
  int f = *flag;
  int t = threadIdx.x;
  int tid = blockIdx.x * 256 + t;
  int e0 = tid, e1 = tid + MSE_S, e2 = tid + 2 * MSE_S, e3 = tid + 3 * MSE_S;  // all < N_EDGES
  // level 1: all edge-index + ep loads
  int s0 = edge_at(ei, 0, e0, f), d0 = edge_at(ei, 1, e0, f);
  int s1 = edge_at(ei, 0, e1, f), d1 = edge_at(ei, 1, e1, f);
  int s2 = edge_at(ei, 0, e2, f), d2 = edge_at(ei, 1, e2, f);
  int s3 = edge_at(ei, 0, e3, f), d3 = edge_at(ei, 1, e3, f);
  float p0 = ep[e0], p1 = ep[e1], p2 = ep[e2], p3 = ep[e3];
  // level 2: all row gathers (16 independent uint4 loads)
  uint4 a00 = fx8[s0*2], a01 = fx8[s0*2+1], b00 = fx8[d0*2], b01 = fx8[d0*2+1];
  uint4 a10 = fx8[s1*2], a11 = fx8[s1*2+1], b10 = fx8[d1*2], b11 = fx8[d1*2+1];
  uint4 a20 = fx8[s2*2], a21 = fx8[s2*2+1], b20 = fx8[d2*2], b21 = fx8[d2*2+1];
  uint4 a30 = fx8[s3*2], a31 = fx8[s3*2+1], b30 = fx8[d3*2], b31 = fx8[d3*2+1];
  // compute
  float f0 = rowdot(a00, a01, b00, b01) - p0;
  float f1 = rowdot(a10, a11, b10, b11) - p1;
  float f2 = rowdot(a20, a21, b20, b21) - p2;
  float f3 = rowdot(a30, a31, b30, b31) - p3;
  float local = f0 * f0 + f1 * f1 + f2 * f2 + f3 * f3;
  __shared__ float sd[256];
  sd[t] = local; __syncthreads();
  for (int off = 128; off > 0; off >>= 1) {
    if (t < off) sd[t] += sd[t + off];
    __syncthreads();
  }
  if (t == 0) atomicAdd(msed, (double)sd[0]);
}

// ---- edge MSE (fallback grid-stride version) ----
__global__ void __launch_bounds__(256) k_msef3(const int* ei, const float* ep,
                                               const uint4* fx8, const int* flag,
                                               double* msed) {
  int f = *flag;
  int tid = blockIdx.x * blockDim.x + threadIdx.x;
  float local = 0.0f;
  for (int e = tid; e < N_EDGES; e += gridDim.x * blockDim.x) {
    int s = edge_at(ei, 0, e, f);
    int d = edge_at(ei, 1, e, f);
    const uint4* rs = fx8 + s * 2;
    const uint4* rd = fx8 + d * 2;
    uint4 a0 = rs[0], a1 = rs[1];
    uint4 b0 = rd[0], b1 = rd[1];
    float acc = rowdot(a0, a1, b0, b1);
    float diff = acc - ep[e];
    local += diff * diff;
  }
  __shared__ float sd[256];
  sd[threadIdx.x] = local; __syncthreads();
  for (int off = 128; off > 0; off >>= 1) {
    if (threadIdx.x < off) sd[threadIdx.x] += sd[threadIdx.x + off];
    __syncthreads();
  }
  if (threadIdx.x == 0) atomicAdd(msed, (double)sd[0]);
}

// ---- column sums of log(1-FX^2) ----
__global__ void __launch_bounds__(256) k_colsumf(const float* FX, float* colsum) {
  __shared__ float sd[256];
  int tid = threadIdx.x;
  int j = tid & 31, g = tid >> 5;
  float local = 0.0f;
  if (j < NCLUS) {
    for (int n = blockIdx.x * 8 + g; n < N_NODES; n += gridDim.x * 8) {
      float v = FX[n * NCLUS + j];
      local += log1pf(-v * v);
    }
  }
  sd[tid] = local; __syncthreads();
  if (tid < 32) {
    float s = 0.0f;
    #pragma unroll
    for (int gg = 0; gg < 8; gg++) s += sd[tid + 32 * gg];
    if (tid < NCLUS) atomicAdd(&colsum[tid], s);
  }
}

// ---- final loss ----
__global__ void k_final(const float* colsum, const double* msed, float* out) {
  int tid = threadIdx.x;
  float v = 0.0f;
  if (tid < NCLUS) v = logf(1.0001f - __expf(colsum[tid]));
  #pragma unroll
  for (int mask = 32; mask > 0; mask >>= 1) v += __shfl_xor(v, mask, 64);
  if (tid == 0) {
    float preg = -v;
    float msev = (float)(*msed / (double)N_EDGES);
    out[(size_t)N_NODES * NCLUS] = msev + 0.01f * preg;
  }
}

extern "C" void kernel_launch(void* const* d_in, const int* in_sizes, int n_in,
                              void* d_out, int out_size, void* d_ws, size_t ws_size,
                              hipStream_t stream) {
  const float* x  = (const float*)d_in[0];
  const int*   ei = (const int*)d_in[1];
  const float* ep = (const float*)d_in[2];
  const float* W1 = (const float*)d_in[3];
  const float* b1 = (const float*)d_in[4];
  const float* W2 = (const float*)d_in[5];
  const float* b2 = (const float*)d_in[6];
  float* out = (float*)d_out;   // fp32: FX[100000*30] then loss scalar

  char* ws = (char*)d_ws;
  size_t off = 0;
  auto alloc = [&](size_t bytes) { size_t o = off; off += (bytes + 255) & ~(size_t)255; return o; };

  size_t o_hdr  = alloc(1024);                       // flag@0, msed@8(double), colsum@256
  size_t o_cnt  = alloc((size_t)N_NODES * 4);
  size_t o_dinv = alloc((size_t)N_NODES * 4);
  size_t o_B1   = alloc((size_t)N_NODES * 32 * 4);   // CSR: G1 bf16 [0,6.4M) + H/tot/bstart [6.4M,...)
  size_t o_B2   = alloc((size_t)N_NODES * 32 * 4);   // CSR: sorted [0,12.8M) -> later fx8[0,3.2M)+G2[3.2M,9.6M)

  int*    flag   = (int*)(ws + o_hdr);
  double* msed   = (double*)(ws + o_hdr + 8);
  float*  colsum = (float*)(ws + o_hdr + 256);
  int*    cnt    = (int*)(ws + o_cnt);
  float*  dinv   = (float*)(ws + o_dinv);
  float*  B1f    = (float*)(ws + o_B1);
  float*  B2f    = (float*)(ws + o_B2);
  __hip_bfloat16* B1b = (__hip_bfloat16*)(ws + o_B1);
  unsigned char*  B2c = (unsigned char*)(ws + o_B2);

  const int nodeBlocks = (N_NODES + 255) / 256;
  const int edgeBlocks = EDGE_BLOCKS;
  const int grpBlocks  = GRP_BLOCKS;
  const int elemBlocks = (N_NODES * 32 + 255) / 256;

  k_detect<<<1, 64, 0, stream>>>((const unsigned int*)ei, flag, colsum, msed);

  size_t o_cursor = alloc((size_t)N_NODES * 4);
  size_t o_csr    = alloc((size_t)N_EDGES * 4);
  bool use_csr = (off <= ws_size);

  const unsigned char* fx8;

  if (use_csr) {
    int* cursor = (int*)(ws + o_cursor);
    int* csr    = (int*)(ws + o_csr);
    // overlays inside B1 upper half (G1 bf16 occupies [0, 6.4M))
    int* H      = (int*)(ws + o_B1 + 6400000);                 // 128*782*4 = 400KB
    int* tot    = (int*)(ws + o_B1 + 6400000 + 401408);        // 782*4
    int* bstart = (int*)(ws + o_B1 + 6400000 + 405504);        // 783*4
    unsigned* sorted = (unsigned*)B2c;                          // B2 [0,12.8M), dead after pass2

    __hip_bfloat16* G1b = B1b;

    // hist || gemmA -> scans -> scat1 || gemmB -> pass2 (+ G1 dinv rescale)
    k_f1<<<PB + G1A_BLK, FTPB, 0, stream>>>(ei, flag, H, x, W1, G1b);
    k_hscan<<<NBUCK, PB, 0, stream>>>(H, tot);
    k_bscan<<<1, 1024, 0, stream>>>(tot, bstart);
    k_f2<<<PB + G1B_BLK, FTPB, 0, stream>>>(ei, flag, H, bstart, sorted, x, W1, G1b);
    k_pass2<<<NBUCK, 256, 0, stream>>>(sorted, bstart, cnt, cursor, dinv, csr, G1b);

    __hip_bfloat16* G2b = (__hip_bfloat16*)(ws + o_B2 + (size_t)N_NODES * 32); // [3.2M,9.6M)
    unsigned char*  fx  = B2c;                                                  // [0,3.2M)

    k_agg1f<<<grpBlocks, 256, 0, stream>>>(G1b, cursor, cnt, csr, dinv, b1, W2, G2b);
    k_agg2c<<<grpBlocks, 256, 0, stream>>>(G2b, cursor, cnt, csr, dinv, b2, out, fx);
    fx8 = fx;

    // exact-sized standalone mse + small colsum (R15: keep them OUT of agg2c)
    k_msee<<<MSE_BLOCKS, 256, 0, stream>>>(ei, ep, (const uint4*)fx8, flag, msed);
    k_colsumf<<<256, 256, 0, stream>>>(out, colsum);
  } else {
    k_zeroall<<<nodeBlocks, 256, 0, stream>>>(cnt, colsum, msed);
    k_count<<<edgeBlocks, 256, 0, stream>>>(ei, flag, cnt);
    k_dinv<<<nodeBlocks, 256, 0, stream>>>(cnt, dinv);
    k_gemm1s<<<grpBlocks, 256, 0, stream>>>(x, W1, dinv, B1f);
    hipMemsetAsync(B2f, 0, (size_t)N_NODES * 32 * 4, stream);
    k_eagg2<<<8192, 256, 0, stream>>>(ei, flag, B1f, B2f);
    k_relu2<<<elemBlocks, 256, 0, stream>>>(B2f, dinv, b1, B1f);
    k_gemm2s<<<grpBlocks, 256, 0, stream>>>(B1f, W2, dinv, B2f);
    hipMemsetAsync(B1f, 0, (size_t)N_NODES * 32 * 4, stream);
    k_eagg2<<<8192, 256, 0, stream>>>(ei, flag, B2f, B1f);
    k_softmax2<<<nodeBlocks, 256, 0, stream>>>(B1f, B2f, dinv, b2, out);
    k_fx8<<<elemBlocks, 256, 0, stream>>>(out, (unsigned char*)B1b);
    fx8 = (const unsigned char*)B1b;
    k_msef3<<<4096, 256, 0, stream>>>(ei, ep, (const uint4*)fx8, flag, msed);
    k_colsumf<<<256, 256, 0, stream>>>(out, colsum);
  }

  k_final<<<1, 64, 0, stream>>>(colsum, msed, out);
}

// Round 17
// 413.025 us; speedup vs baseline: 1.2926x; 1.0540x over previous
//
#include <hip/hip_runtime.h>
#include <hip/hip_bf16.h>
#include <hip/hip_fp8.h>

#define N_NODES 100000
#define N_EDGES 3200000
#define IN_DIM  128
#define HID     32
#define NCLUS   30
#define EDGE_BLOCKS 12500 // ceil(3200000/256)
#define GRP_BLOCKS  12500 // ceil(100000/8)

// ---- counting-sort geometry ----
#define BUCK_SHIFT 7
#define BUCK_W     128
#define NBUCK      782
#define PB         128                 // pass-1 blocks (128B per (block,bucket) run)
#define EPB        25000               // 128*25000 = 3.2M exact
#define SEG_CAP    8192
#define FTPB       512                 // threads per fused block

// ---- gemm1 row-per-lane geometry: 512 rows/block (lane owns a row; W1 in LDS) ----
#define G1A_BLK    98                  // 98*512 = 50176 rows in k_f1
#define G1A_ROWS   50176
#define G1B_BLK    98                  // rows [50176,100000) guarded, in k_f2

// ---- loss geometry: COLSUM blocks FIRST (R13 tail lesson), then exact-sized MSE.
//      3125*256*4 = 3.2M edges exact, no guards. R16: msee is request-count bound
//      (12.8M divergent 16B gathers); geometry-invariant at ~63us. Fusing colsum
//      in FRONT overlaps its ~10us instead of serializing it. ----
#define COL_BLOCKS 256
#define MSE_BLOCKS 3125
#define MSE_S      (MSE_BLOCKS * 256)  // 800000

__device__ __forceinline__ float bf2f(__hip_bfloat16 v) { return __bfloat162float(v); }

// fp8 e4m3 (OCP) encode/decode via HW cvt
__device__ __forceinline__ unsigned char enc8(float v) {
  __hip_fp8_e4m3 t(v); return (unsigned char)t.__x;
}
__device__ __forceinline__ float dec8(unsigned b) {
  __hip_fp8_e4m3 t; t.__x = (__hip_fp8_storage_t)b; return (float)t;
}
__device__ __forceinline__ float dot4_fp8(unsigned a, unsigned b) {
  float r = 0.0f;
  #pragma unroll
  for (int k = 0; k < 4; k++)
    r += dec8((a >> (8 * k)) & 0xffu) * dec8((b >> (8 * k)) & 0xffu);
  return r;
}

// packed dot of 4 fp8 pairs: HW packed cvt (2 floats/instr, OCP e4m3 on gfx950)
typedef float floatx2 __attribute__((ext_vector_type(2)));
__device__ __forceinline__ float dot4p(unsigned a, unsigned b) {
#if __has_builtin(__builtin_amdgcn_cvt_pk_f32_fp8)
  floatx2 al = __builtin_amdgcn_cvt_pk_f32_fp8((int)a, false);
  floatx2 ah = __builtin_amdgcn_cvt_pk_f32_fp8((int)a, true);
  floatx2 bl = __builtin_amdgcn_cvt_pk_f32_fp8((int)b, false);
  floatx2 bh = __builtin_amdgcn_cvt_pk_f32_fp8((int)b, true);
  return al[0]*bl[0] + al[1]*bl[1] + ah[0]*bh[0] + ah[1]*bh[1];
#else
  return dot4_fp8(a, b);
#endif
}
__device__ __forceinline__ float rowdot(const uint4& a0, const uint4& a1,
                                        const uint4& b0, const uint4& b1) {
  return dot4p(a0.x, b0.x) + dot4p(a0.y, b0.y) + dot4p(a0.z, b0.z) + dot4p(a0.w, b0.w)
       + dot4p(a1.x, b1.x) + dot4p(a1.y, b1.y) + dot4p(a1.z, b1.z) + dot4p(a1.w, b1.w);
}

// scale a packed pair of bf16 by sc (RNE via __float2bfloat16)
__device__ __forceinline__ unsigned sc2(unsigned u, float sc) {
  __hip_bfloat16 h0 = *reinterpret_cast<__hip_bfloat16*>(&u);
  unsigned uh = u >> 16;
  __hip_bfloat16 h1 = *reinterpret_cast<__hip_bfloat16*>(&uh);
  __hip_bfloat16 r0 = __float2bfloat16(__bfloat162float(h0) * sc);
  __hip_bfloat16 r1 = __float2bfloat16(__bfloat162float(h1) * sc);
  unsigned a = *reinterpret_cast<unsigned short*>(&r0);
  unsigned b = *reinterpret_cast<unsigned short*>(&r1);
  return a | (b << 16);
}

// edge_index accessor: f=0 -> int32 layout, f=1 -> int64 layout (read low word)
__device__ __forceinline__ int edge_at(const int* ei, int row, int e, int f) {
  int v = ei[(row * N_EDGES + e) << f];
  return min(max(v, 0), N_NODES - 1);
}

// ---- detect int32 vs int64 edge_index + zero loss scalars ----
__global__ void k_detect(const unsigned int* ei, int* flag, float* colsum, double* msed) {
  int t = threadIdx.x;
  if (t < 32) colsum[t] = 0.0f;
  if (t == 32) *msed = 0.0;
  if (t == 0) {
    int zeros = 0;
    for (int i = 1; i < 128; i += 2) zeros += (ei[i] == 0u) ? 1 : 0;
    *flag = (zeros >= 48) ? 1 : 0;
  }
}

// ---- zero cnt + loss scalars (fallback path) ----
__global__ void k_zeroall(int* cnt, float* colsum, double* msed) {
  int t = blockIdx.x * blockDim.x + threadIdx.x;
  if (t < N_NODES) cnt[t] = 0;
  if (t < 32) colsum[t] = 0.0f;
  if (t == 32) *msed = 0.0;
}

// ---- GEMM1 row-per-lane body: lane owns row n; x per-lane float4 (distinct lines),
//      W1 broadcast from LDS. UNSCALED bf16 out (dinv applied in k_pass2 rescale). ----
__device__ __forceinline__ void gemm1_rpl(int gb, int row_off, const float* x,
                                          const float* Wl, __hip_bfloat16* G1) {
  int n = row_off + gb * FTPB + threadIdx.x;
  if (n >= N_NODES) return;
  float acc[32];
  #pragma unroll
  for (int j = 0; j < 32; j++) acc[j] = 0.0f;
  const float4* xp = (const float4*)(x + (size_t)n * IN_DIM);
  #pragma unroll
  for (int kc = 0; kc < 4; kc++) {          // 4 chunks of 32 k
    float4 xv[8];
    #pragma unroll
    for (int q = 0; q < 8; q++) xv[q] = xp[kc * 8 + q];
    #pragma unroll
    for (int q = 0; q < 8; q++) {
      #pragma unroll
      for (int e = 0; e < 4; e++) {
        float xk = (e == 0) ? xv[q].x : (e == 1) ? xv[q].y : (e == 2) ? xv[q].z : xv[q].w;
        const float4* wr = (const float4*)(Wl + (kc * 32 + q * 4 + e) * HID);
        #pragma unroll
        for (int jv = 0; jv < 8; jv++) {    // 8 x float4 = 32 cols
          float4 w4 = wr[jv];               // uniform addr -> LDS broadcast
          acc[4*jv+0] += xk * w4.x;
          acc[4*jv+1] += xk * w4.y;
          acc[4*jv+2] += xk * w4.z;
          acc[4*jv+3] += xk * w4.w;
        }
      }
    }
  }
  unsigned pk[16];
  #pragma unroll
  for (int jp = 0; jp < 16; jp++) {
    __hip_bfloat16 l0 = __float2bfloat16(acc[2*jp]);
    __hip_bfloat16 l1 = __float2bfloat16(acc[2*jp+1]);
    unsigned a = *reinterpret_cast<unsigned short*>(&l0);
    unsigned b = *reinterpret_cast<unsigned short*>(&l1);
    pk[jp] = a | (b << 16);
  }
  uint4* dst = (uint4*)(G1 + (size_t)n * 32);   // 64B = lane-owned line
  dst[0] = make_uint4(pk[0], pk[1], pk[2], pk[3]);
  dst[1] = make_uint4(pk[4], pk[5], pk[6], pk[7]);
  dst[2] = make_uint4(pk[8], pk[9], pk[10], pk[11]);
  dst[3] = make_uint4(pk[12], pk[13], pk[14], pk[15]);
}

// ---- FUSED 1: blocks [0,PB) = LDS bucket histogram (4-deep prefetch); rest = gemmA ----
__global__ void __launch_bounds__(FTPB) k_f1(const int* ei, const int* flag, int* H,
                                             const float* x, const float* W1, __hip_bfloat16* G1) {
  __shared__ float smem[IN_DIM * HID];           // 16KB: Wl for gemm / h[] for hist
  int t = threadIdx.x;
  if (blockIdx.x >= PB) {
    for (int i = t; i < IN_DIM * HID; i += FTPB) smem[i] = W1[i];
    __syncthreads();
    gemm1_rpl(blockIdx.x - PB, 0, x, smem, G1);
    return;
  }
  int* h = (int*)smem;
  int p = blockIdx.x;
  for (int i = t; i < NBUCK; i += FTPB) h[i] = 0;
  __syncthreads();
  int f = *flag;
  int base = p * EPB;
  int i = t;
  for (; i + 3 * FTPB < EPB; i += 4 * FTPB) {
    int d0 = edge_at(ei, 1, base + i,            f);
    int d1 = edge_at(ei, 1, base + i + FTPB,     f);
    int d2 = edge_at(ei, 1, base + i + 2 * FTPB, f);
    int d3 = edge_at(ei, 1, base + i + 3 * FTPB, f);
    atomicAdd(&h[d0 >> BUCK_SHIFT], 1);
    atomicAdd(&h[d1 >> BUCK_SHIFT], 1);
    atomicAdd(&h[d2 >> BUCK_SHIFT], 1);
    atomicAdd(&h[d3 >> BUCK_SHIFT], 1);
  }
  for (; i < EPB; i += FTPB) {
    int d = edge_at(ei, 1, base + i, f);
    atomicAdd(&h[d >> BUCK_SHIFT], 1);
  }
  __syncthreads();
  for (int q = t; q < NBUCK; q += FTPB) H[p * NBUCK + q] = h[q];
}

// ---- sort scan A: column-scan of H over PB blocks -> exclusive in place + bucket totals ----
__global__ void __launch_bounds__(PB) k_hscan(int* H, int* tot) {
  __shared__ int s[PB];
  int b = blockIdx.x, t = threadIdx.x;
  int v = H[t * NBUCK + b];
  s[t] = v; __syncthreads();
  for (int off = 1; off < PB; off <<= 1) {
    int u = (t >= off) ? s[t - off] : 0;
    __syncthreads();
    s[t] += u;
    __syncthreads();
  }
  H[t * NBUCK + b] = s[t] - v;               // exclusive prefix within bucket column
  if (t == PB - 1) tot[b] = s[t];
}

// ---- sort scan B: exclusive scan of bucket totals -> bstart[0..NBUCK] ----
__global__ void __launch_bounds__(1024) k_bscan(const int* tot, int* bstart) {
  __shared__ int s[1024];
  int t = threadIdx.x;
  int v = (t < NBUCK) ? tot[t] : 0;
  s[t] = v; __syncthreads();
  for (int off = 1; off < 1024; off <<= 1) {
    int u = (t >= off) ? s[t - off] : 0;
    __syncthreads();
    s[t] += u;
    __syncthreads();
  }
  if (t < NBUCK) bstart[t] = s[t] - v;
  if (t == NBUCK - 1) bstart[NBUCK] = s[t];  // = N_EDGES
}

// ---- FUSED 2: blocks [0,PB) = scatter (4-deep prefetch); rest = gemmB ----
__global__ void __launch_bounds__(FTPB) k_f2(const int* ei, const int* flag, const int* H,
                                             const int* bstart, unsigned* sorted,
                                             const float* x, const float* W1, __hip_bfloat16* G1) {
  __shared__ float smem[IN_DIM * HID];           // 16KB: Wl for gemm / cur[] for scatter
  int t = threadIdx.x;
  if (blockIdx.x >= PB) {
    for (int i = t; i < IN_DIM * HID; i += FTPB) smem[i] = W1[i];
    __syncthreads();
    gemm1_rpl(blockIdx.x - PB, G1A_ROWS, x, smem, G1);
    return;
  }
  int* cur = (int*)smem;
  int p = blockIdx.x;
  for (int i = t; i < NBUCK; i += FTPB) cur[i] = bstart[i] + H[p * NBUCK + i];
  __syncthreads();
  int f = *flag;
  int base = p * EPB;
  int i = t;
  for (; i + 3 * FTPB < EPB; i += 4 * FTPB) {
    int e0 = base + i, e1 = e0 + FTPB, e2 = e0 + 2 * FTPB, e3 = e0 + 3 * FTPB;
    int s0 = edge_at(ei, 0, e0, f), d0 = edge_at(ei, 1, e0, f);
    int s1 = edge_at(ei, 0, e1, f), d1 = edge_at(ei, 1, e1, f);
    int s2 = edge_at(ei, 0, e2, f), d2 = edge_at(ei, 1, e2, f);
    int s3 = edge_at(ei, 0, e3, f), d3 = edge_at(ei, 1, e3, f);
    int sl0 = atomicAdd(&cur[d0 >> BUCK_SHIFT], 1);
    int sl1 = atomicAdd(&cur[d1 >> BUCK_SHIFT], 1);
    int sl2 = atomicAdd(&cur[d2 >> BUCK_SHIFT], 1);
    int sl3 = atomicAdd(&cur[d3 >> BUCK_SHIFT], 1);
    sorted[sl0] = ((unsigned)s0 << BUCK_SHIFT) | (unsigned)(d0 & (BUCK_W - 1));
    sorted[sl1] = ((unsigned)s1 << BUCK_SHIFT) | (unsigned)(d1 & (BUCK_W - 1));
    sorted[sl2] = ((unsigned)s2 << BUCK_SHIFT) | (unsigned)(d2 & (BUCK_W - 1));
    sorted[sl3] = ((unsigned)s3 << BUCK_SHIFT) | (unsigned)(d3 & (BUCK_W - 1));
  }
  for (; i < EPB; i += FTPB) {
    int e = base + i;
    int s = edge_at(ei, 0, e, f);
    int d = edge_at(ei, 1, e, f);
    int slot = atomicAdd(&cur[d >> BUCK_SHIFT], 1);
    sorted[slot] = ((unsigned)s << BUCK_SHIFT) | (unsigned)(d & (BUCK_W - 1));
  }
}

// ---- sort pass 2: one block per bucket: LDS count + scan -> cnt/cursor/dinv + exact CSR,
//      then in-place dinv rescale of this bucket's G1 rows (vectorized uint4 = 8 bf16). ----
__global__ void __launch_bounds__(256) k_pass2(const unsigned* sorted, const int* bstart,
                                               int* cnt, int* cursor, float* dinv, int* csr,
                                               __hip_bfloat16* G1) {
  __shared__ unsigned se[SEG_CAP];
  __shared__ int scnt[BUCK_W], soff[BUCK_W], scur[BUCK_W];
  __shared__ float sdv[BUCK_W];
  int b = blockIdx.x, t = threadIdx.x;
  int s0 = bstart[b], s1 = bstart[b + 1], len = s1 - s0;
  for (int i = t; i < len && i < SEG_CAP; i += 256) se[i] = sorted[s0 + i];
  if (t < BUCK_W) scnt[t] = 0;
  __syncthreads();
  for (int i = t; i < len; i += 256) {
    unsigned u = (i < SEG_CAP) ? se[i] : sorted[s0 + i];
    atomicAdd(&scnt[u & (BUCK_W - 1)], 1);
  }
  __syncthreads();
  int c = (t < BUCK_W) ? scnt[t] : 0;
  if (t < BUCK_W) soff[t] = c;
  __syncthreads();
  for (int off = 1; off < BUCK_W; off <<= 1) {
    int u = 0;
    if (t >= off && t < BUCK_W) u = soff[t - off];
    __syncthreads();
    if (t < BUCK_W) soff[t] += u;
    __syncthreads();
  }
  if (t < BUCK_W) {
    int ex = soff[t] - c;                    // exclusive local offset
    int node = (b << BUCK_SHIFT) + t;
    float dv = rsqrtf((float)(c + 1));
    sdv[t] = dv;
    if (node < N_NODES) {
      cnt[node] = c;
      cursor[node] = s0 + ex;
      dinv[node] = dv;
    }
    scur[t] = ex;                            // running cursor starts at exclusive offset
  }
  __syncthreads();
  for (int i = t; i < len; i += 256) {
    unsigned u = (i < SEG_CAP) ? se[i] : sorted[s0 + i];
    int dl = u & (BUCK_W - 1);
    int r = atomicAdd(&scur[dl], 1);
    csr[s0 + r] = (int)(u >> BUCK_SHIFT);
  }
  // ---- in-place G1 rescale for this bucket's nodes (G1 written unscaled by f1/f2) ----
  int nbase = b << BUCK_SHIFT;
  int nlim = min(BUCK_W, N_NODES - nbase);   // nodes in this bucket
  uint4* Gv = (uint4*)(G1 + (size_t)nbase * 32);
  for (int q = t; q < nlim * 4; q += 256) {  // 4 uint4 (8 bf16 each) per 32-col row
    float sc = sdv[q >> 2];
    uint4 u = Gv[q];
    u.x = sc2(u.x, sc); u.y = sc2(u.y, sc);
    u.z = sc2(u.z, sc); u.w = sc2(u.w, sc);
    Gv[q] = u;
  }
}

// ---- plain count (fallback path) ----
__global__ void k_count(const int* ei, const int* flag, int* cnt) {
  int e = blockIdx.x * blockDim.x + threadIdx.x;
  if (e >= N_EDGES) return;
  int f = *flag;
  atomicAdd(&cnt[edge_at(ei, 1, e, f)], 1);
}

// ---- dinv (fallback path) ----
__global__ void k_dinv(const int* cnt, float* dinv) {
  int t = blockIdx.x * blockDim.x + threadIdx.x;
  if (t < N_NODES) dinv[t] = rsqrtf((float)(cnt[t] + 1));
}

// ---- FUSED agg1 + gemm2: gather pre-scaled G1 -> h in reg ->
//      G2[n,j] = (sum_k shfl(h,k)*W2[k,j]) * dinv[n], bf16 out.
//      16-deep gather unroll: all row loads issued before accumulation (MLP). ----
__global__ void __launch_bounds__(256) k_agg1f(const __hip_bfloat16* G, const int* cursor,
                                               const int* cnt, const int* csr, const float* dinv,
                                               const float* b1, const float* W2,
                                               __hip_bfloat16* G2) {
  int j = threadIdx.x & 31, g = threadIdx.x >> 5;
  int n = blockIdx.x * 8 + g;
  if (n >= N_NODES) return;
  int len = cnt[n];
  int st = cursor[n];
  float dn = dinv[n];
  float acc = bf2f(G[n * 32 + j]);        // self loop (pre-scaled)
  int i = 0;
  for (; i + 16 <= len; i += 16) {
    int s[16];
    #pragma unroll
    for (int q = 0; q < 16; q++) s[q] = csr[st + i + q];
    float v[16];
    #pragma unroll
    for (int q = 0; q < 16; q++) v[q] = bf2f(G[s[q] * 32 + j]);
    #pragma unroll
    for (int q = 0; q < 16; q++) acc += v[q];
  }
  for (; i + 4 <= len; i += 4) {
    int s[4];
    #pragma unroll
    for (int q = 0; q < 4; q++) s[q] = csr[st + i + q];
    float v[4];
    #pragma unroll
    for (int q = 0; q < 4; q++) v[q] = bf2f(G[s[q] * 32 + j]);
    #pragma unroll
    for (int q = 0; q < 4; q++) acc += v[q];
  }
  for (; i < len; i++) acc += bf2f(G[csr[st + i] * 32 + j]);
  float h = fmaxf(dn * acc + b1[j], 0.0f);
  float g2 = 0.0f;
  #pragma unroll
  for (int k = 0; k < HID; k++) {
    float wk = (j < NCLUS) ? W2[k * NCLUS + j] : 0.0f;   // L1-hot after first group
    g2 += __shfl(h, k, 32) * wk;
  }
  G2[n * 32 + j] = __float2bfloat16((j < NCLUS) ? g2 * dn : 0.0f);
}

// ---- CSR agg layer2 (pre-scaled G2), 16-deep gather + softmax -> out + fx8.
//      NO colsum fusion (R15: barrier+LDS here -> VGPR 32 -> gather serialized, 2x). ----
__global__ void __launch_bounds__(256) k_agg2c(const __hip_bfloat16* G, const int* cursor,
                                               const int* cnt, const int* csr, const float* dinv,
                                               const float* b2, float* outp, unsigned char* fx8) {
  int j = threadIdx.x & 31, g = threadIdx.x >> 5;
  int n = blockIdx.x * 8 + g;
  if (n >= N_NODES) return;
  int len = cnt[n];
  int st = cursor[n];
  float acc = bf2f(G[n * 32 + j]);
  int i = 0;
  for (; i + 16 <= len; i += 16) {
    int s[16];
    #pragma unroll
    for (int q = 0; q < 16; q++) s[q] = csr[st + i + q];
    float v[16];
    #pragma unroll
    for (int q = 0; q < 16; q++) v[q] = bf2f(G[s[q] * 32 + j]);
    #pragma unroll
    for (int q = 0; q < 16; q++) acc += v[q];
  }
  for (; i + 4 <= len; i += 4) {
    int s[4];
    #pragma unroll
    for (int q = 0; q < 4; q++) s[q] = csr[st + i + q];
    float v[4];
    #pragma unroll
    for (int q = 0; q < 4; q++) v[q] = bf2f(G[s[q] * 32 + j]);
    #pragma unroll
    for (int q = 0; q < 4; q++) acc += v[q];
  }
  for (; i < len; i++) acc += bf2f(G[csr[st + i] * 32 + j]);
  bool act = (j < NCLUS);
  float logit = act ? fminf(fmaxf(dinv[n] * acc + b2[j], -80.0f), 80.0f) : -1e30f;
  float m = logit;
  #pragma unroll
  for (int mask = 16; mask > 0; mask >>= 1) m = fmaxf(m, __shfl_xor(m, mask, 32));
  float ex = act ? __expf(logit - m) : 0.0f;
  float ssum = ex;
  #pragma unroll
  for (int mask = 16; mask > 0; mask >>= 1) ssum += __shfl_xor(ssum, mask, 32);
  float fx = ex / fmaxf(ssum, 1e-30f);
  if (act) outp[n * NCLUS + j] = fx;
  fx8[n * 32 + j] = enc8(act ? fx : 0.0f);
}

// ---- fallback fp32 kernels (atomic path) ----
__global__ void __launch_bounds__(256) k_gemm1s(const float* x, const float* W1,
                                                const float* dinv, float* G1) {
  __shared__ float Ws[IN_DIM * HID];
  int tid = threadIdx.x;
  for (int i = tid; i < IN_DIM * HID; i += 256) Ws[i] = W1[i];
  __syncthreads();
  int j = tid & 31, r = tid >> 5;
  int n = blockIdx.x * 8 + r;
  if (n >= N_NODES) return;
  const float* xr = x + (size_t)n * IN_DIM;
  float acc = 0.0f;
  #pragma unroll
  for (int k = 0; k < IN_DIM; k++) acc += xr[k] * Ws[k * HID + j];
  G1[n * 32 + j] = acc * dinv[n];
}

__global__ void __launch_bounds__(256) k_gemm2s(const float* h, const float* W2,
                                                const float* dinv, float* G2) {
  __shared__ float Ws[HID * 32];
  int tid = threadIdx.x;
  for (int i = tid; i < HID * 32; i += 256) Ws[i] = 0.0f;
  __syncthreads();
  for (int i = tid; i < HID * NCLUS; i += 256) {
    int k = i / NCLUS, j = i % NCLUS;
    Ws[k * 32 + j] = W2[i];
  }
  __syncthreads();
  int j = tid & 31, r = tid >> 5;
  int n = blockIdx.x * 8 + r;
  if (n >= N_NODES) return;
  const float* hr = h + (size_t)n * 32;
  float acc = 0.0f;
  #pragma unroll
  for (int k = 0; k < HID; k++) acc += hr[k] * Ws[k * 32 + j];
  G2[n * 32 + j] = (j < NCLUS) ? acc * dinv[n] : 0.0f;
}

__global__ void __launch_bounds__(256) k_eagg2(const int* ei, const int* flag,
                                               const float* G, float* D) {
  int j = threadIdx.x & 31, g = threadIdx.x >> 5;
  int f = *flag;
  for (int e = blockIdx.x * 8 + g; e < N_EDGES; e += gridDim.x * 8) {
    int s = edge_at(ei, 0, e, f);
    int d = edge_at(ei, 1, e, f);
    atomicAdd(&D[d * 32 + j], G[s * 32 + j]);
  }
}

__global__ void k_relu2(const float* A, const float* dinv, const float* b1, float* G) {
  int t = blockIdx.x * blockDim.x + threadIdx.x;
  if (t >= N_NODES * 32) return;
  int n = t >> 5, j = t & 31;
  G[t] = fmaxf(dinv[n] * (A[t] + G[t]) + b1[j], 0.0f);
}

__global__ void __launch_bounds__(256) k_softmax2(const float* S, const float* G2, const float* dinv,
                                                  const float* b2, float* outp) {
  int n = blockIdx.x * blockDim.x + threadIdx.x;
  if (n >= N_NODES) return;
  float di = dinv[n];
  float lg[NCLUS];
  float m = -1e30f;
  #pragma unroll
  for (int j = 0; j < NCLUS; j++) {
    float v = di * (S[n * 32 + j] + G2[n * 32 + j]) + b2[j];
    v = fminf(fmaxf(v, -80.0f), 80.0f);
    lg[j] = v; m = fmaxf(m, v);
  }
  float ssum = 0.0f;
  #pragma unroll
  for (int j = 0; j < NCLUS; j++) { lg[j] = __expf(lg[j] - m); ssum += lg[j]; }
  float inv = 1.0f / ssum;
  #pragma unroll
  for (int j = 0; j < NCLUS; j++) outp[n * NCLUS + j] = lg[j] * inv;
}

// ---- out (fp32, stride 30) -> fx8 (fp8, stride 32), fallback path ----
__global__ void k_fx8(const float* outp, unsigned char* fx8) {
  int t = blockIdx.x * blockDim.x + threadIdx.x;
  if (t >= N_NODES * 32) return;
  int n = t >> 5, j = t & 31;
  fx8[t] = enc8((j < NCLUS) ? outp[n * NCLUS + j] : 0.0f);
}

// ---- FUSED loss v2: COLSUM blocks FIRST [0,COL_BLOCKS), then exact-sized MSE.
//      R13 failed with colsum LAST (serial tail); col-first overlaps it fully. ----
__global__ void __launch_bounds__(256) k_msl(const int* ei, const float* ep,
                                             const uint4* fx8, const int* flag,
                                             const float* FX,
                                             double* msed, float* colsum) {
  __shared__ float sd[256];
  int t = threadIdx.x;
  if (blockIdx.x < COL_BLOCKS) {
    // ---- colsum role: column sums of log(1-FX^2), dispatched first ----
    int cb = blockIdx.x;
    int j = t & 31, g = t >> 5;
    float local = 0.0f;
    if (j < NCLUS) {
      for (int n = cb * 8 + g; n < N_NODES; n += COL_BLOCKS * 8) {
        float v = FX[n * NCLUS + j];
        local += log1pf(-v * v);
      }
    }
    sd[t] = local; __syncthreads();
    if (t < 32) {
      float s = 0.0f;
      #pragma unroll
      for (int gg = 0; gg < 8; gg++) s += sd[t + 32 * gg];
      if (t < NCLUS) atomicAdd(&colsum[t], s);
    }
    return;
  }
  int f = *flag;
  int tid = (blockIdx.x - COL_BLOCKS) * 256 + t;
  int e0 = tid, e1 = tid + MSE_S, e2 = tid + 2 * MSE_S, e3 = tid + 3 * MSE_S;  // all < N_EDGES
  // level 1: all edge-index + ep loads
  int s0 = edge_at(ei, 0, e0, f), d0 = edge_at(ei, 1, e0, f);
  int s1 = edge_at(ei, 0, e1, f), d1 = edge_at(ei, 1, e1, f);
  int s2 = edge_at(ei, 0, e2, f), d2 = edge_at(ei, 1, e2, f);
  int s3 = edge_at(ei, 0, e3, f), d3 = edge_at(ei, 1, e3, f);
  float p0 = ep[e0], p1 = ep[e1], p2 = ep[e2], p3 = ep[e3];
  // level 2: all row gathers (16 independent uint4 loads)
  uint4 a00 = fx8[s0*2], a01 = fx8[s0*2+1], b00 = fx8[d0*2], b01 = fx8[d0*2+1];
  uint4 a10 = fx8[s1*2], a11 = fx8[s1*2+1], b10 = fx8[d1*2], b11 = fx8[d1*2+1];
  uint4 a20 = fx8[s2*2], a21 = fx8[s2*2+1], b20 = fx8[d2*2], b21 = fx8[d2*2+1];
  uint4 a30 = fx8[s3*2], a31 = fx8[s3*2+1], b30 = fx8[d3*2], b31 = fx8[d3*2+1];
  // compute
  float f0 = rowdot(a00, a01, b00, b01) - p0;
  float f1 = rowdot(a10, a11, b10, b11) - p1;
  float f2 = rowdot(a20, a21, b20, b21) - p2;
  float f3 = rowdot(a30, a31, b30, b31) - p3;
  float local = f0 * f0 + f1 * f1 + f2 * f2 + f3 * f3;
  sd[t] = local; __syncthreads();
  for (int off = 128; off > 0; off >>= 1) {
    if (t < off) sd[t] += sd[t + off];
    __syncthreads();
  }
  if (t == 0) atomicAdd(msed, (double)sd[0]);
}

// ---- edge MSE (fallback grid-stride version) ----
__global__ void __launch_bounds__(256) k_msef3(const int* ei, const float* ep,
                                               const uint4* fx8, const int* flag,
                                               double* msed) {
  int f = *flag;
  int tid = blockIdx.x * blockDim.x + threadIdx.x;
  float local = 0.0f;
  for (int e = tid; e < N_EDGES; e += gridDim.x * blockDim.x) {
    int s = edge_at(ei, 0, e, f);
    int d = edge_at(ei, 1, e, f);
    const uint4* rs = fx8 + s * 2;
    const uint4* rd = fx8 + d * 2;
    uint4 a0 = rs[0], a1 = rs[1];
    uint4 b0 = rd[0], b1 = rd[1];
    float acc = rowdot(a0, a1, b0, b1);
    float diff = acc - ep[e];
    local += diff * diff;
  }
  __shared__ float sd[256];
  sd[threadIdx.x] = local; __syncthreads();
  for (int off = 128; off > 0; off >>= 1) {
    if (threadIdx.x < off) sd[threadIdx.x] += sd[threadIdx.x + off];
    __syncthreads();
  }
  if (threadIdx.x == 0) atomicAdd(msed, (double)sd[0]);
}

// ---- column sums of log(1-FX^2) (fallback path) ----
__global__ void __launch_bounds__(256) k_colsumf(const float* FX, float* colsum) {
  __shared__ float sd[256];
  int tid = threadIdx.x;
  int j = tid & 31, g = tid >> 5;
  float local = 0.0f;
  if (j < NCLUS) {
    for (int n = blockIdx.x * 8 + g; n < N_NODES; n += gridDim.x * 8) {
      float v = FX[n * NCLUS + j];
      local += log1pf(-v * v);
    }
  }
  sd[tid] = local; __syncthreads();
  if (tid < 32) {
    float s = 0.0f;
    #pragma unroll
    for (int gg = 0; gg < 8; gg++) s += sd[tid + 32 * gg];
    if (tid < NCLUS) atomicAdd(&colsum[tid], s);
  }
}

// ---- final loss ----
__global__ void k_final(const float* colsum, const double* msed, float* out) {
  int tid = threadIdx.x;
  float v = 0.0f;
  if (tid < NCLUS) v = logf(1.0001f - __expf(colsum[tid]));
  #pragma unroll
  for (int mask = 32; mask > 0; mask >>= 1) v += __shfl_xor(v, mask, 64);
  if (tid == 0) {
    float preg = -v;
    float msev = (float)(*msed / (double)N_EDGES);
    out[(size_t)N_NODES * NCLUS] = msev + 0.01f * preg;
  }
}

extern "C" void kernel_launch(void* const* d_in, const int* in_sizes, int n_in,
                              void* d_out, int out_size, void* d_ws, size_t ws_size,
                              hipStream_t stream) {
  const float* x  = (const float*)d_in[0];
  const int*   ei = (const int*)d_in[1];
  const float* ep = (const float*)d_in[2];
  const float* W1 = (const float*)d_in[3];
  const float* b1 = (const float*)d_in[4];
  const float* W2 = (const float*)d_in[5];
  const float* b2 = (const float*)d_in[6];
  float* out = (float*)d_out;   // fp32: FX[100000*30] then loss scalar

  char* ws = (char*)d_ws;
  size_t off = 0;
  auto alloc = [&](size_t bytes) { size_t o = off; off += (bytes + 255) & ~(size_t)255; return o; };

  size_t o_hdr  = alloc(1024);                       // flag@0, msed@8(double), colsum@256
  size_t o_cnt  = alloc((size_t)N_NODES * 4);
  size_t o_dinv = alloc((size_t)N_NODES * 4);
  size_t o_B1   = alloc((size_t)N_NODES * 32 * 4);   // CSR: G1 bf16 [0,6.4M) + H/tot/bstart [6.4M,...)
  size_t o_B2   = alloc((size_t)N_NODES * 32 * 4);   // CSR: sorted [0,12.8M) -> later fx8[0,3.2M)+G2[3.2M,9.6M)

  int*    flag   = (int*)(ws + o_hdr);
  double* msed   = (double*)(ws + o_hdr + 8);
  float*  colsum = (float*)(ws + o_hdr + 256);
  int*    cnt    = (int*)(ws + o_cnt);
  float*  dinv   = (float*)(ws + o_dinv);
  float*  B1f    = (float*)(ws + o_B1);
  float*  B2f    = (float*)(ws + o_B2);
  __hip_bfloat16* B1b = (__hip_bfloat16*)(ws + o_B1);
  unsigned char*  B2c = (unsigned char*)(ws + o_B2);

  const int nodeBlocks = (N_NODES + 255) / 256;
  const int edgeBlocks = EDGE_BLOCKS;
  const int grpBlocks  = GRP_BLOCKS;
  const int elemBlocks = (N_NODES * 32 + 255) / 256;

  k_detect<<<1, 64, 0, stream>>>((const unsigned int*)ei, flag, colsum, msed);

  size_t o_cursor = alloc((size_t)N_NODES * 4);
  size_t o_csr    = alloc((size_t)N_EDGES * 4);
  bool use_csr = (off <= ws_size);

  const unsigned char* fx8;

  if (use_csr) {
    int* cursor = (int*)(ws + o_cursor);
    int* csr    = (int*)(ws + o_csr);
    // overlays inside B1 upper half (G1 bf16 occupies [0, 6.4M))
    int* H      = (int*)(ws + o_B1 + 6400000);                 // 128*782*4 = 400KB
    int* tot    = (int*)(ws + o_B1 + 6400000 + 401408);        // 782*4
    int* bstart = (int*)(ws + o_B1 + 6400000 + 405504);        // 783*4
    unsigned* sorted = (unsigned*)B2c;                          // B2 [0,12.8M), dead after pass2

    __hip_bfloat16* G1b = B1b;

    // hist || gemmA -> scans -> scat1 || gemmB -> pass2 (+ G1 dinv rescale)
    k_f1<<<PB + G1A_BLK, FTPB, 0, stream>>>(ei, flag, H, x, W1, G1b);
    k_hscan<<<NBUCK, PB, 0, stream>>>(H, tot);
    k_bscan<<<1, 1024, 0, stream>>>(tot, bstart);
    k_f2<<<PB + G1B_BLK, FTPB, 0, stream>>>(ei, flag, H, bstart, sorted, x, W1, G1b);
    k_pass2<<<NBUCK, 256, 0, stream>>>(sorted, bstart, cnt, cursor, dinv, csr, G1b);

    __hip_bfloat16* G2b = (__hip_bfloat16*)(ws + o_B2 + (size_t)N_NODES * 32); // [3.2M,9.6M)
    unsigned char*  fx  = B2c;                                                  // [0,3.2M)

    k_agg1f<<<grpBlocks, 256, 0, stream>>>(G1b, cursor, cnt, csr, dinv, b1, W2, G2b);
    k_agg2c<<<grpBlocks, 256, 0, stream>>>(G2b, cursor, cnt, csr, dinv, b2, out, fx);
    fx8 = fx;

    // fused loss: colsum blocks FIRST, then exact-sized mse
    k_msl<<<COL_BLOCKS + MSE_BLOCKS, 256, 0, stream>>>(ei, ep, (const uint4*)fx8, flag,
                                                       out, msed, colsum);
  } else {
    k_zeroall<<<nodeBlocks, 256, 0, stream>>>(cnt, colsum, msed);
    k_count<<<edgeBlocks, 256, 0, stream>>>(ei, flag, cnt);
    k_dinv<<<nodeBlocks, 256, 0, stream>>>(cnt, dinv);
    k_gemm1s<<<grpBlocks, 256, 0, stream>>>(x, W1, dinv, B1f);
    hipMemsetAsync(B2f, 0, (size_t)N_NODES * 32 * 4, stream);
    k_eagg2<<<8192, 256, 0, stream>>>(ei, flag, B1f, B2f);
    k_relu2<<<elemBlocks, 256, 0, stream>>>(B2f, dinv, b1, B1f);
    k_gemm2s<<<grpBlocks, 256, 0, stream>>>(B1f, W2, dinv, B2f);
    hipMemsetAsync(B1f, 0, (size_t)N_NODES * 32 * 4, stream);
    k_eagg2<<<8192, 256, 0, stream>>>(ei, flag, B2f, B1f);
    k_softmax2<<<nodeBlocks, 256, 0, stream>>>(B1f, B2f, dinv, b2, out);
    k_fx8<<<elemBlocks, 256, 0, stream>>>(out, (unsigned char*)B1b);
    fx8 = (const unsigned char*)B1b;
    k_msef3<<<4096, 256, 0, stream>>>(ei, ep, (const uint4*)fx8, flag, msed);
    k_colsumf<<<256, 256, 0, stream>>>(out, colsum);
  }

  k_final<<<1, 64, 0, stream>>>(colsum, msed, out);
}